// Round 1
// baseline (12728.512 us; speedup 1.0000x reference)
//
#include <hip/hip_runtime.h>
#include <cstddef>

// ---- problem constants ----
// N=128, C_IN=64, C_OUT=64, T=128, V=25, K=3, G=8, REL=8, D=192
#define MTOT 409600.0f   // N*T*V

// ---- d_out scratch offsets (floats); out_size = 26,214,400 ----
#define DO_ATT 0          // [128][3][64][25][25] = 15,360,000
#define DO_XM  15360000   // [128][64][25]        = 204,800
#define DO_GP  15564800   // [256][4160]          = 1,064,960 (ends 16,629,760)

// ---- ws offsets (floats); need ~26.5M floats (~106 MB) ----
#define WS_YBUF 0          // [128][64][128][25] = 26,214,400
#define WS_BN2P 26214400   // [2048][64][2]      = 262,144
#define WS_NA   26476544   // [3][8][25][25]     = 15,000
#define WS_PAR  26491552   // A1[192] B1C[192] A2[64] B2C[64]

// ============ K1: Gram partials (G = x0 x0^T over samples) + M1 ============
__global__ __launch_bounds__(256) void k_gram(const float* __restrict__ x0,
                                              float* __restrict__ gp) {
  __shared__ float Xs[64 * 65];
  int b = blockIdx.x, tid = threadIdx.x;
  int n = b >> 1;
  int tv0 = (b & 1) * 1600;
  const float* xb = x0 + (size_t)n * (64 * 3200);
  float g[4][4];
#pragma unroll
  for (int a = 0; a < 4; a++)
#pragma unroll
    for (int bb = 0; bb < 4; bb++) g[a][bb] = 0.f;
  float m1 = 0.f;
  int ci0 = (tid >> 4) * 4, cj0 = (tid & 15) * 4;
  for (int sub = 0; sub < 25; sub++) {
    __syncthreads();
    for (int idx = tid; idx < 4096; idx += 256) {
      int c = idx >> 6, s = idx & 63;
      Xs[c * 65 + s] = xb[c * 3200 + tv0 + sub * 64 + s];
    }
    __syncthreads();
    if (tid < 64) {
      float s = 0.f;
#pragma unroll
      for (int su = 0; su < 64; su++) s += Xs[tid * 65 + su];
      m1 += s;
    }
    for (int s = 0; s < 64; s++) {
      float bv[4];
#pragma unroll
      for (int bb = 0; bb < 4; bb++) bv[bb] = Xs[(cj0 + bb) * 65 + s];
#pragma unroll
      for (int a = 0; a < 4; a++) {
        float av = Xs[(ci0 + a) * 65 + s];
#pragma unroll
        for (int bb = 0; bb < 4; bb++) g[a][bb] += av * bv[bb];
      }
    }
  }
  float* o = gp + (size_t)b * 4160;
#pragma unroll
  for (int a = 0; a < 4; a++)
#pragma unroll
    for (int bb = 0; bb < 4; bb++) o[(ci0 + a) * 64 + (cj0 + bb)] = g[a][bb];
  if (tid < 64) o[4096 + tid] = m1;
}

// ============ K2: reduce Gram -> BN1 fold params; also norm_A ============
__global__ __launch_bounds__(256) void k_params(const float* __restrict__ dsc,
                                                const float* __restrict__ DA,
                                                const float* __restrict__ Lw,
                                                const float* __restrict__ g0,
                                                const float* __restrict__ b0,
                                                float* __restrict__ ws) {
  __shared__ float Gs[4096];
  __shared__ float m1s[64];
  __shared__ float Hh[32 * 192];
  int tid = threadIdx.x;
  const float* gp = dsc + DO_GP;
  // norm_A: column-normalize the tiled adjacency
  for (int col = tid; col < 600; col += 256) {
    int k = col / 200, g = (col / 25) % 8, w = col % 25;
    const float* base = DA + (k * 8 + g) * 625 + w;
    float s = 0.f;
    for (int v = 0; v < 25; v++) s += base[v * 25];
    float inv = 1.0f / (s + 0.001f);
    for (int v = 0; v < 25; v++)
      ws[WS_NA + (k * 8 + g) * 625 + v * 25 + w] = base[v * 25] * inv;
  }
  if (tid < 64) {
    float s = 0.f;
    for (int b = 0; b < 256; b++) s += gp[(size_t)b * 4160 + 4096 + tid];
    m1s[tid] = s;
  }
  for (int idx = tid; idx < 4096; idx += 256) {
    float s = 0.f;
    for (int b = 0; b < 256; b++) s += gp[(size_t)b * 4160 + idx];
    Gs[idx] = s;
  }
  __syncthreads();
  float exacc = 0.f;
  for (int p = 0; p < 2; p++) {
    for (int idx = tid; idx < 6144; idx += 256) {
      int cl = idx / 192, d = idx % 192;
      int c = p * 32 + cl;
      float acc = 0.f;
      for (int c2 = 0; c2 < 64; c2++) acc += Gs[c * 64 + c2] * Lw[c2 * 192 + d];
      Hh[cl * 192 + d] = acc;
    }
    __syncthreads();
    if (tid < 192) {
      for (int cl = 0; cl < 32; cl++)
        exacc += Lw[(p * 32 + cl) * 192 + tid] * Hh[cl * 192 + tid];
    }
    __syncthreads();
  }
  if (tid < 192) {
    float mu = 0.f;
    for (int c = 0; c < 64; c++) mu += m1s[c] * Lw[c * 192 + tid];
    mu *= (1.0f / MTOT);
    float ex2 = exacc * (1.0f / MTOT);
    float var = ex2 - mu * mu;
    float a1 = g0[tid] * rsqrtf(var + 1e-5f);
    ws[WS_PAR + tid] = a1;
    ws[WS_PAR + 192 + tid] = b0[tid] - a1 * mu;  // Linear_bias cancels in BN
  }
}

// ============ K3: xm = mean over T ============
__global__ __launch_bounds__(256) void k_xm(const float* __restrict__ x0,
                                            float* __restrict__ dsc) {
  __shared__ float red[8][32];
  int bid = blockIdx.x;
  int n = bid >> 6, c = bid & 63;
  int tid = threadIdx.x;
  int tq = tid >> 5, v = tid & 31;
  const float* xb = x0 + (size_t)(n * 64 + c) * 3200;
  float s = 0.f;
  if (v < 25) {
    for (int j = 0; j < 16; j++) s += xb[(tq + 8 * j) * 25 + v];
  }
  red[tq][v] = s;
  __syncthreads();
  if (tq == 0 && v < 25) {
    float tot = 0.f;
#pragma unroll
    for (int q = 0; q < 8; q++) tot += red[q][v];
    dsc[DO_XM + (size_t)(n * 64 + c) * 25 + v] = tot * (1.0f / 128.0f);
  }
}

// ============ K4: attention tensors att[n,i,o,u,w] ============
__global__ __launch_bounds__(256) void k_att(float* __restrict__ dsc,
    const float* __restrict__ w1, const float* __restrict__ b1,
    const float* __restrict__ w2, const float* __restrict__ b2,
    const float* __restrict__ w4, const float* __restrict__ b4,
    const float* __restrict__ Ag, const float* __restrict__ alpha) {
  __shared__ float xms[1600];
  __shared__ float x1s[200];
  __shared__ float x2s[200];
  __shared__ float Td[5000];
  int bid = blockIdx.x, tid = threadIdx.x;
  int n = bid / 3, i = bid % 3;
  for (int idx = tid; idx < 1600; idx += 256)
    xms[idx] = dsc[DO_XM + (size_t)n * 1600 + idx];
  __syncthreads();
  for (int idx = tid; idx < 400; idx += 256) {
    int r = (idx % 200) / 25, u = idx % 25;
    const float* wv = (idx < 200 ? w1 : w2) + (i * 8 + r) * 64;
    float acc = (idx < 200 ? b1 : b2)[i * 8 + r];
    for (int c = 0; c < 64; c++) acc += xms[c * 25 + u] * wv[c];
    if (idx < 200) x1s[r * 25 + u] = acc; else x2s[r * 25 + u] = acc;
  }
  __syncthreads();
  for (int idx = tid; idx < 5000; idx += 256) {
    int r = idx / 625, u = (idx % 625) / 25, w = idx % 25;
    Td[idx] = tanhf(x1s[r * 25 + u] - x2s[r * 25 + w]);
  }
  __syncthreads();
  float al = alpha[0];
  for (int idx = tid; idx < 40000; idx += 256) {
    int o = idx / 625, uw = idx % 625;
    float acc = b4[i * 64 + o];
#pragma unroll
    for (int r = 0; r < 8; r++) acc += w4[(i * 64 + o) * 8 + r] * Td[r * 625 + uw];
    dsc[DO_ATT + ((size_t)(n * 3 + i) * 64 + o) * 625 + uw] = al * acc + Ag[i * 625 + uw];
  }
}

// ============ K6: y-branch (x3 = w3*x0, y = att @ x3) per (n, c-quad) ============
__global__ __launch_bounds__(256) void k_ybr(const float* __restrict__ x0,
                                             const float* __restrict__ dsc,
                                             const float* __restrict__ w3,
                                             const float* __restrict__ b3,
                                             float* __restrict__ ws) {
  __shared__ float atts[7500];   // [3][4][25][25]
  __shared__ float xs2[6400];    // [64][4][25]
  __shared__ float x3s[1200];    // [3][4][4][25]
  __shared__ float w3s[768];
  __shared__ float b3s[12];
  int bid = blockIdx.x, tid = threadIdx.x;
  int n = bid >> 4, c0 = (bid & 15) * 4;
  for (int idx = tid; idx < 7500; idx += 256) {
    int i = idx / 2500, r = idx % 2500;
    atts[idx] = dsc[DO_ATT + ((size_t)(n * 3 + i) * 64 + c0) * 625 + r];
  }
  for (int idx = tid; idx < 768; idx += 256) {
    int i = idx / 256, cc = (idx % 256) / 64, e = idx & 63;
    w3s[idx] = w3[(i * 64 + c0 + cc) * 64 + e];
  }
  if (tid < 12) b3s[tid] = b3[(tid >> 2) * 64 + c0 + (tid & 3)];
  const float* xn = x0 + (size_t)n * 204800;
  float* yb = ws + WS_YBUF + (size_t)n * 204800;
  for (int t0 = 0; t0 < 128; t0 += 4) {
    __syncthreads();
    for (int idx = tid; idx < 6400; idx += 256) {
      int e = idx / 100, r = idx % 100;
      xs2[idx] = xn[e * 3200 + t0 * 25 + r];
    }
    __syncthreads();
    for (int idx = tid; idx < 1200; idx += 256) {
      int i = idx / 400, rem = idx % 400, cc = rem / 100, ttv = rem % 100;
      float acc = b3s[i * 4 + cc];
      const float* wrow = &w3s[(i * 4 + cc) * 64];
      for (int e = 0; e < 64; e++) acc += wrow[e] * xs2[e * 100 + ttv];
      x3s[idx] = acc;
    }
    __syncthreads();
    for (int idx = tid; idx < 400; idx += 256) {
      int cc = idx / 100, tt = (idx % 100) / 25, v = idx % 25;
      float acc = 0.f;
#pragma unroll
      for (int i = 0; i < 3; i++) {
        const float* ar = &atts[(i * 4 + cc) * 625 + v];
        const float* xr = &x3s[(i * 4 + cc) * 100 + tt * 25];
#pragma unroll
        for (int u = 0; u < 25; u++) acc += ar[u * 25] * xr[u];
      }
      yb[(size_t)(c0 + cc) * 3200 + (t0 + tt) * 25 + v] = acc;
    }
  }
}

// ===== K5: main fused: Linear+BN1 fold, graph contraction, ensemble, BN2 partials =====
__global__ __launch_bounds__(256) void k_main(const float* __restrict__ x0,
                                              const float* __restrict__ Lw,
                                              const float* __restrict__ ensw,
                                              const float* __restrict__ ensb,
                                              float* __restrict__ ws,
                                              float* __restrict__ dout) {
  __shared__ float xs[1600];    // x0[n,:,t,:]
  __shared__ float xh[4800];    // BN-folded linear output [192][25]
  __shared__ float xbv[1600];   // x-branch [64][25]
  __shared__ float ys[1600];    // y-branch slice [64][25]
  __shared__ float red[512];
  int bid = blockIdx.x, tid = threadIdx.x;
  int n = bid >> 4, t0 = (bid & 15) * 8;
  const float* xn = x0 + (size_t)n * 204800;
  const float* yb = ws + WS_YBUF + (size_t)n * 204800;
  float lsum = 0.f, lss = 0.f;
  for (int tj = 0; tj < 8; tj++) {
    int t = t0 + tj;
    __syncthreads();
    for (int idx = tid; idx < 1600; idx += 256) {
      int c = idx / 25, v = idx % 25;
      int off = c * 3200 + t * 25 + v;
      xs[idx] = xn[off];
      ys[idx] = yb[off];
    }
    __syncthreads();
    if (tid < 192) {
      int d = tid;
      float acc[25];
#pragma unroll
      for (int v = 0; v < 25; v++) acc[v] = 0.f;
      for (int c = 0; c < 64; c++) {
        float w = Lw[c * 192 + d];
#pragma unroll
        for (int v = 0; v < 25; v++) acc[v] += xs[c * 25 + v] * w;
      }
      float a1 = ws[WS_PAR + d], b1c = ws[WS_PAR + 192 + d];
#pragma unroll
      for (int v = 0; v < 25; v++) xh[d * 25 + v] = a1 * acc[v] + b1c;
    }
    __syncthreads();
    {
      int c = tid >> 2, wq = tid & 3;
      int g = c & 7;
      float acc[7];
#pragma unroll
      for (int j = 0; j < 7; j++) acc[j] = 0.f;
      for (int k = 0; k < 3; k++) {
        const float* xrow = &xh[(k * 64 + c) * 25];
        const float* na = &ws[WS_NA + (k * 8 + g) * 625];
        for (int v = 0; v < 25; v++) {
          float a = xrow[v];
          const float* nav = na + v * 25;
#pragma unroll
          for (int j = 0; j < 7; j++) {
            int w = wq + 4 * j;
            if (w < 25) acc[j] += a * nav[w];
          }
        }
      }
#pragma unroll
      for (int j = 0; j < 7; j++) {
        int w = wq + 4 * j;
        if (w < 25) xbv[c * 25 + w] = acc[j];
      }
    }
    __syncthreads();
    {
      int o = tid >> 2, vq = tid & 3;
      float eb = ensb[o];
      float acc[7];
#pragma unroll
      for (int j = 0; j < 7; j++) acc[j] = eb;
      for (int c = 0; c < 64; c++) {
        float w1e = ensw[o * 128 + c], w2e = ensw[o * 128 + 64 + c];
        const float* xr = &xbv[c * 25];
        const float* yr = &ys[c * 25];
#pragma unroll
        for (int j = 0; j < 7; j++) {
          int v = vq + 4 * j;
          if (v < 25) acc[j] += xr[v] * w1e + yr[v] * w2e;
        }
      }
      size_t ob = (size_t)(n * 64 + o) * 3200 + (size_t)t * 25;
#pragma unroll
      for (int j = 0; j < 7; j++) {
        int v = vq + 4 * j;
        if (v < 25) {
          float val = acc[j];
          dout[ob + v] = val;
          lsum += val;
          lss += val * val;
        }
      }
    }
  }
  red[tid] = lsum;
  red[256 + tid] = lss;
  __syncthreads();
  if ((tid & 3) == 0) {
    int o = tid >> 2;
    float s = red[tid] + red[tid + 1] + red[tid + 2] + red[tid + 3];
    float ss = red[256 + tid] + red[256 + tid + 1] + red[256 + tid + 2] + red[256 + tid + 3];
    ws[WS_BN2P + (size_t)bid * 128 + o * 2] = s;
    ws[WS_BN2P + (size_t)bid * 128 + o * 2 + 1] = ss;
  }
}

// ============ K9: BN2 reduce ============
__global__ __launch_bounds__(256) void k_bn2(const float* __restrict__ g2,
                                             const float* __restrict__ b2,
                                             float* __restrict__ ws) {
  int tid = threadIdx.x;
  if (tid < 64) {
    float s = 0.f, ss = 0.f;
    for (int b = 0; b < 2048; b++) {
      s += ws[WS_BN2P + (size_t)b * 128 + tid * 2];
      ss += ws[WS_BN2P + (size_t)b * 128 + tid * 2 + 1];
    }
    float mu = s / MTOT;
    float var = ss / MTOT - mu * mu;
    float a2 = g2[tid] * rsqrtf(var + 1e-5f);
    ws[WS_PAR + 384 + tid] = a2;
    ws[WS_PAR + 448 + tid] = b2[tid] - a2 * mu;
  }
}

// ============ K10: final BN2 apply + residual + ReLU (in-place on d_out) ============
__global__ __launch_bounds__(256) void k_final(const float* __restrict__ x0,
                                               const float* __restrict__ ws,
                                               float* __restrict__ dout) {
  size_t g = (size_t)blockIdx.x * 256 + threadIdx.x;
  float4 p = reinterpret_cast<const float4*>(dout)[g];
  float4 x = reinterpret_cast<const float4*>(x0)[g];
  int o = (int)((g * 4 / 3200) & 63);
  float a2 = ws[WS_PAR + 384 + o], bc = ws[WS_PAR + 448 + o];
  float4 r;
  r.x = fmaxf(fmaf(a2, p.x, bc) + x.x, 0.f);
  r.y = fmaxf(fmaf(a2, p.y, bc) + x.y, 0.f);
  r.z = fmaxf(fmaf(a2, p.z, bc) + x.z, 0.f);
  r.w = fmaxf(fmaf(a2, p.w, bc) + x.w, 0.f);
  reinterpret_cast<float4*>(dout)[g] = r;
}

extern "C" void kernel_launch(void* const* d_in, const int* in_sizes, int n_in,
                              void* d_out, int out_size, void* d_ws, size_t ws_size,
                              hipStream_t stream) {
  const float* x0    = (const float*)d_in[0];
  const float* DA    = (const float*)d_in[1];
  const float* Ag    = (const float*)d_in[2];
  const float* alpha = (const float*)d_in[3];
  const float* w1    = (const float*)d_in[4];
  const float* b1    = (const float*)d_in[5];
  const float* w2    = (const float*)d_in[6];
  const float* b2    = (const float*)d_in[7];
  const float* w3    = (const float*)d_in[8];
  const float* b3    = (const float*)d_in[9];
  const float* w4    = (const float*)d_in[10];
  const float* b4    = (const float*)d_in[11];
  const float* Lw    = (const float*)d_in[12];
  // d_in[13] Linear_bias: provably cancels under training-mode BN — unused
  const float* g0    = (const float*)d_in[14];
  const float* b0    = (const float*)d_in[15];
  const float* ensw  = (const float*)d_in[16];
  const float* ensb  = (const float*)d_in[17];
  const float* g2    = (const float*)d_in[18];
  const float* b2n   = (const float*)d_in[19];
  float* out = (float*)d_out;
  float* ws  = (float*)d_ws;

  k_gram<<<256, 256, 0, stream>>>(x0, out + DO_GP);
  k_xm<<<8192, 256, 0, stream>>>(x0, out);
  k_params<<<1, 256, 0, stream>>>(out, DA, Lw, g0, b0, ws);
  k_att<<<384, 256, 0, stream>>>(out, w1, b1, w2, b2, w4, b4, Ag, alpha);
  k_ybr<<<2048, 256, 0, stream>>>(x0, out, w3, b3, ws);
  k_main<<<2048, 256, 0, stream>>>(x0, Lw, ensw, ensb, ws, out);
  k_bn2<<<1, 256, 0, stream>>>(g2, b2n, ws);
  k_final<<<25600, 256, 0, stream>>>(x0, ws, out);
}

// Round 2
// 3164.761 us; speedup vs baseline: 4.0220x; 4.0220x over previous
//
#include <hip/hip_runtime.h>
#include <cstddef>

// ---- problem constants ----
// N=128, C_IN=64, C_OUT=64, T=128, V=25, K=3, G=8, REL=8, D=192
#define MTOT 409600.0f   // N*T*V

// ---- d_out scratch offsets (floats); out_size = 26,214,400 ----
#define DO_ATT 0          // [128][3][64][25][25] = 15,360,000
#define DO_XM  15360000   // [128][64][25]        = 204,800
#define DO_GP  15564800   // [256][4160]          = 1,064,960

// ---- ws offsets (floats) ----
#define WS_YBUF 0          // [128][64][128][25] = 26,214,400
#define WS_BN2P 26214400   // [2048][64][2]      = 262,144
#define WS_NA   26476544   // [3][8][25][25]     = 15,000 (fp32)
#define WS_PAR  26491552   // A1[192] B1C[192] A2[64] B2C[64] = 512
#define WS_LWF  26492064   // [3][64][64] = 12,288 (a1-folded Lw, [k][c][e])
#define WS_CB   26504352   // [64][25] = 1,600 (bias-through-contraction)

static __device__ __forceinline__ ushort f2b(float f) {
  unsigned u = __float_as_uint(f);
  return (ushort)((u + 0x7FFFu + ((u >> 16) & 1u)) >> 16);
}
static __device__ __forceinline__ float b2f(ushort b) {
  return __uint_as_float(((unsigned)b) << 16);
}

// ============ K1: Gram partials (G = x0 x0^T over samples) + M1 ============
__global__ __launch_bounds__(256) void k_gram(const float* __restrict__ x0,
                                              float* __restrict__ gp) {
  __shared__ float Xs[64 * 65];
  int b = blockIdx.x, tid = threadIdx.x;
  int n = b >> 1;
  int tv0 = (b & 1) * 1600;
  const float* xb = x0 + (size_t)n * (64 * 3200);
  float g[4][4];
#pragma unroll
  for (int a = 0; a < 4; a++)
#pragma unroll
    for (int bb = 0; bb < 4; bb++) g[a][bb] = 0.f;
  float m1 = 0.f;
  int ci0 = (tid >> 4) * 4, cj0 = (tid & 15) * 4;
  for (int sub = 0; sub < 25; sub++) {
    __syncthreads();
    for (int idx = tid; idx < 4096; idx += 256) {
      int c = idx >> 6, s = idx & 63;
      Xs[c * 65 + s] = xb[c * 3200 + tv0 + sub * 64 + s];
    }
    __syncthreads();
    if (tid < 64) {
      float s = 0.f;
#pragma unroll
      for (int su = 0; su < 64; su++) s += Xs[tid * 65 + su];
      m1 += s;
    }
    for (int s = 0; s < 64; s++) {
      float bv[4];
#pragma unroll
      for (int bb = 0; bb < 4; bb++) bv[bb] = Xs[(cj0 + bb) * 65 + s];
#pragma unroll
      for (int a = 0; a < 4; a++) {
        float av = Xs[(ci0 + a) * 65 + s];
#pragma unroll
        for (int bb = 0; bb < 4; bb++) g[a][bb] += av * bv[bb];
      }
    }
  }
  float* o = gp + (size_t)b * 4160;
#pragma unroll
  for (int a = 0; a < 4; a++)
#pragma unroll
    for (int bb = 0; bb < 4; bb++) o[(ci0 + a) * 64 + (cj0 + bb)] = g[a][bb];
  if (tid < 64) o[4096 + tid] = m1;
}

// ===== K2: reduce Gram -> BN1 fold params; norm_A; folded LwF; cb =====
__global__ __launch_bounds__(256) void k_params(const float* __restrict__ dsc,
                                                const float* __restrict__ DA,
                                                const float* __restrict__ Lw,
                                                const float* __restrict__ g0,
                                                const float* __restrict__ b0,
                                                float* __restrict__ ws) {
  __shared__ float Gs[4096];
  __shared__ float m1s[64];
  __shared__ float Hh[32 * 192];
  __shared__ float a1s[192];
  __shared__ float b1s[192];
  int tid = threadIdx.x;
  const float* gp = dsc + DO_GP;
  // norm_A
  for (int col = tid; col < 600; col += 256) {
    int k = col / 200, g = (col / 25) % 8, w = col % 25;
    const float* base = DA + (k * 8 + g) * 625 + w;
    float s = 0.f;
    for (int v = 0; v < 25; v++) s += base[v * 25];
    float inv = 1.0f / (s + 0.001f);
    for (int v = 0; v < 25; v++)
      ws[WS_NA + (k * 8 + g) * 625 + v * 25 + w] = base[v * 25] * inv;
  }
  if (tid < 64) {
    float s = 0.f;
    for (int b = 0; b < 256; b++) s += gp[(size_t)b * 4160 + 4096 + tid];
    m1s[tid] = s;
  }
  for (int idx = tid; idx < 4096; idx += 256) {
    float s = 0.f;
    for (int b = 0; b < 256; b++) s += gp[(size_t)b * 4160 + idx];
    Gs[idx] = s;
  }
  __syncthreads();
  float exacc = 0.f;
  for (int p = 0; p < 2; p++) {
    for (int idx = tid; idx < 6144; idx += 256) {
      int cl = idx / 192, d = idx % 192;
      int c = p * 32 + cl;
      float acc = 0.f;
      for (int c2 = 0; c2 < 64; c2++) acc += Gs[c * 64 + c2] * Lw[c2 * 192 + d];
      Hh[cl * 192 + d] = acc;
    }
    __syncthreads();
    if (tid < 192) {
      for (int cl = 0; cl < 32; cl++)
        exacc += Lw[(p * 32 + cl) * 192 + tid] * Hh[cl * 192 + tid];
    }
    __syncthreads();
  }
  if (tid < 192) {
    float mu = 0.f;
    for (int c = 0; c < 64; c++) mu += m1s[c] * Lw[c * 192 + tid];
    mu *= (1.0f / MTOT);
    float ex2 = exacc * (1.0f / MTOT);
    float var = ex2 - mu * mu;
    float a1 = g0[tid] * rsqrtf(var + 1e-5f);
    float b1c = b0[tid] - a1 * mu;  // Linear_bias cancels in training-mode BN
    a1s[tid] = a1; b1s[tid] = b1c;
    ws[WS_PAR + tid] = a1;
    ws[WS_PAR + 192 + tid] = b1c;
  }
  __syncthreads();
  // folded weights LwF[k][c][e] = a1[k*64+c] * Lw[e][k*64+c]
  for (int idx = tid; idx < 12288; idx += 256) {
    int k = idx >> 12, c = (idx >> 6) & 63, e = idx & 63;
    ws[WS_LWF + idx] = a1s[k * 64 + c] * Lw[e * 192 + k * 64 + c];
  }
  // cb[c][w] = sum_k b1c[k*64+c] * sum_v NA[k][c&7][v][w]
  for (int idx = tid; idx < 1600; idx += 256) {
    int c = idx / 25, w = idx % 25, g = c & 7;
    float s = 0.f;
    for (int k = 0; k < 3; k++) {
      float cs = 0.f;
      const float* na = &ws[WS_NA + (k * 8 + g) * 625 + w];
      for (int v = 0; v < 25; v++) cs += na[v * 25];
      s += b1s[k * 64 + c] * cs;
    }
    ws[WS_CB + idx] = s;
  }
}

// ============ K3: xm = mean over T ============
__global__ __launch_bounds__(256) void k_xm(const float* __restrict__ x0,
                                            float* __restrict__ dsc) {
  __shared__ float red[8][32];
  int bid = blockIdx.x;
  int n = bid >> 6, c = bid & 63;
  int tid = threadIdx.x;
  int tq = tid >> 5, v = tid & 31;
  const float* xb = x0 + (size_t)(n * 64 + c) * 3200;
  float s = 0.f;
  if (v < 25) {
    for (int j = 0; j < 16; j++) s += xb[(tq + 8 * j) * 25 + v];
  }
  red[tq][v] = s;
  __syncthreads();
  if (tq == 0 && v < 25) {
    float tot = 0.f;
#pragma unroll
    for (int q = 0; q < 8; q++) tot += red[q][v];
    dsc[DO_XM + (size_t)(n * 64 + c) * 25 + v] = tot * (1.0f / 128.0f);
  }
}

// ============ K4: attention tensors att[n,i,o,u,w] ============
__global__ __launch_bounds__(256) void k_att(float* __restrict__ dsc,
    const float* __restrict__ w1, const float* __restrict__ b1,
    const float* __restrict__ w2, const float* __restrict__ b2,
    const float* __restrict__ w4, const float* __restrict__ b4,
    const float* __restrict__ Ag, const float* __restrict__ alpha) {
  __shared__ float xms[1600];
  __shared__ float x1s[200];
  __shared__ float x2s[200];
  __shared__ float Td[5000];
  int bid = blockIdx.x, tid = threadIdx.x;
  int n = bid / 3, i = bid % 3;
  for (int idx = tid; idx < 1600; idx += 256)
    xms[idx] = dsc[DO_XM + (size_t)n * 1600 + idx];
  __syncthreads();
  for (int idx = tid; idx < 400; idx += 256) {
    int r = (idx % 200) / 25, u = idx % 25;
    const float* wv = (idx < 200 ? w1 : w2) + (i * 8 + r) * 64;
    float acc = (idx < 200 ? b1 : b2)[i * 8 + r];
    for (int c = 0; c < 64; c++) acc += xms[c * 25 + u] * wv[c];
    if (idx < 200) x1s[r * 25 + u] = acc; else x2s[r * 25 + u] = acc;
  }
  __syncthreads();
  for (int idx = tid; idx < 5000; idx += 256) {
    int r = idx / 625, u = (idx % 625) / 25, w = idx % 25;
    Td[idx] = tanhf(x1s[r * 25 + u] - x2s[r * 25 + w]);
  }
  __syncthreads();
  float al = alpha[0];
  for (int idx = tid; idx < 40000; idx += 256) {
    int o = idx / 625, uw = idx % 625;
    float acc = b4[i * 64 + o];
#pragma unroll
    for (int r = 0; r < 8; r++) acc += w4[(i * 64 + o) * 8 + r] * Td[r * 625 + uw];
    dsc[DO_ATT + ((size_t)(n * 3 + i) * 64 + o) * 625 + uw] = al * acc + Ag[i * 625 + uw];
  }
}

// ============ K6: y-branch (x3 = w3*x0, y = att @ x3) per (n, c-quad) ============
__global__ __launch_bounds__(256) void k_ybr(const float* __restrict__ x0,
                                             const float* __restrict__ dsc,
                                             const float* __restrict__ w3,
                                             const float* __restrict__ b3,
                                             float* __restrict__ ws) {
  __shared__ float atts[7500];   // [3][4][25][25]
  __shared__ float xs2[6400];    // [64][4][25]
  __shared__ float x3s[1200];    // [3][4][4][25]
  __shared__ float w3s[768];
  __shared__ float b3s[12];
  int bid = blockIdx.x, tid = threadIdx.x;
  int n = bid >> 4, c0 = (bid & 15) * 4;
  for (int idx = tid; idx < 7500; idx += 256) {
    int i = idx / 2500, r = idx % 2500;
    atts[idx] = dsc[DO_ATT + ((size_t)(n * 3 + i) * 64 + c0) * 625 + r];
  }
  for (int idx = tid; idx < 768; idx += 256) {
    int i = idx / 256, cc = (idx % 256) / 64, e = idx & 63;
    w3s[idx] = w3[(i * 64 + c0 + cc) * 64 + e];
  }
  if (tid < 12) b3s[tid] = b3[(tid >> 2) * 64 + c0 + (tid & 3)];
  const float* xn = x0 + (size_t)n * 204800;
  float* yb = ws + WS_YBUF + (size_t)n * 204800;
  for (int t0 = 0; t0 < 128; t0 += 4) {
    __syncthreads();
    for (int idx = tid; idx < 6400; idx += 256) {
      int e = idx / 100, r = idx % 100;
      xs2[idx] = xn[e * 3200 + t0 * 25 + r];
    }
    __syncthreads();
    for (int idx = tid; idx < 1200; idx += 256) {
      int i = idx / 400, rem = idx % 400, cc = rem / 100, ttv = rem % 100;
      float acc = b3s[i * 4 + cc];
      const float* wrow = &w3s[(i * 4 + cc) * 64];
      for (int e = 0; e < 64; e++) acc += wrow[e] * xs2[e * 100 + ttv];
      x3s[idx] = acc;
    }
    __syncthreads();
    for (int idx = tid; idx < 400; idx += 256) {
      int cc = idx / 100, tt = (idx % 100) / 25, v = idx % 25;
      float acc = 0.f;
#pragma unroll
      for (int i = 0; i < 3; i++) {
        const float* ar = &atts[(i * 4 + cc) * 625 + v];
        const float* xr = &x3s[(i * 4 + cc) * 100 + tt * 25];
#pragma unroll
        for (int u = 0; u < 25; u++) acc += ar[u * 25] * xr[u];
      }
      yb[(size_t)(c0 + cc) * 3200 + (t0 + tt) * 25 + v] = acc;
    }
  }
}

// ===== K5a: fused Linear(+BN1-fold) + graph contraction -> xb into d_out =====
// block = (n, t-tile of 8); thread = (c=tid>>2, sq=tid&3); halves of 4 t.
__global__ __launch_bounds__(256) void k_linc(const float* __restrict__ x0,
                                              const float* __restrict__ ws,
                                              float* __restrict__ dout) {
  __shared__ ushort NAs[15000];     // [3][8][25*25] bf16
  __shared__ ushort LwFs[64 * 66];  // [c][e] padded (kills 16-way bank conflict)
  __shared__ ushort xsb[6400];      // [e][s]  s = tl*25+v
  __shared__ ushort xhb[6400];      // [c][s]  (reused as output stage)
  int bid = blockIdx.x, tid = threadIdx.x;
  int n = bid >> 4, t0 = (bid & 15) * 8;
  const float* xn = x0 + (size_t)n * 204800;
  for (int idx = tid; idx < 15000; idx += 256) NAs[idx] = f2b(ws[WS_NA + idx]);
  int c = tid >> 2, sq = tid & 3, g = c & 7;
  for (int h = 0; h < 2; ++h) {
    int tt0 = t0 + h * 4;
    __syncthreads();
    for (int idx = tid; idx < 6400; idx += 256) {
      int e = idx / 100, s = idx - e * 100;
      xsb[idx] = f2b(xn[e * 3200 + tt0 * 25 + s]);
    }
    float acc[4][7];
#pragma unroll
    for (int tl = 0; tl < 4; tl++)
#pragma unroll
      for (int wj = 0; wj < 7; wj++) acc[tl][wj] = 0.f;
    for (int k = 0; k < 3; ++k) {
      for (int idx = tid; idx < 4096; idx += 256) {
        int cc = idx >> 6, e = idx & 63;
        LwFs[cc * 66 + e] = f2b(ws[WS_LWF + k * 4096 + idx]);
      }
      __syncthreads();
      // linear: xh[c][s] = sum_e LwF[c][e] * x[e][s], 25 outputs/thread in 5x5
      for (int j5 = 0; j5 < 5; ++j5) {
        float t5[5] = {0.f, 0.f, 0.f, 0.f, 0.f};
        int s0 = sq + 20 * j5;
        for (int e = 0; e < 64; ++e) {
          float w = b2f(LwFs[c * 66 + e]);
          const ushort* xr = &xsb[e * 100 + s0];
#pragma unroll
          for (int q = 0; q < 5; ++q) t5[q] = fmaf(w, b2f(xr[4 * q]), t5[q]);
        }
#pragma unroll
        for (int q = 0; q < 5; ++q) xhb[c * 100 + s0 + 4 * q] = f2b(t5[q]);
      }
      __syncthreads();
      // contract: acc[tl][wj] += sum_v xh[c][tl*25+v] * NA[k][g][v][w]
      const ushort* nab = &NAs[(k * 8 + g) * 625];
#pragma unroll
      for (int tl = 0; tl < 4; ++tl) {
        const ushort* xr = &xhb[c * 100 + tl * 25];
        for (int v = 0; v < 25; ++v) {
          float xv = b2f(xr[v]);
          const ushort* nr = &nab[v * 25 + sq];
#pragma unroll
          for (int wj = 0; wj < 7; ++wj) {
            int w = sq + 4 * wj;
            if (w < 25) acc[tl][wj] = fmaf(xv, b2f(nr[4 * wj]), acc[tl][wj]);
          }
        }
      }
      __syncthreads();  // xhb/LwFs free for next k
    }
    // stage outputs (bf16) for coalesced store
#pragma unroll
    for (int wj = 0; wj < 7; ++wj) {
      int w = sq + 4 * wj;
      if (w < 25) {
        float cbv = ws[WS_CB + c * 25 + w];
#pragma unroll
        for (int tl = 0; tl < 4; ++tl)
          xhb[c * 100 + tl * 25 + w] = f2b(acc[tl][wj] + cbv);
      }
    }
    __syncthreads();
    float* ob = dout + (size_t)n * 204800 + (size_t)tt0 * 25;
    for (int idx = tid; idx < 6400; idx += 256) {
      int cc = idx / 100, s = idx - cc * 100;
      ob[cc * 3200 + s] = b2f(xhb[idx]);
    }
  }
}

// ===== K5b: ensemble (K=128) + BN2 partials, in-place on d_out =====
__global__ __launch_bounds__(256) void k_ens(const float* __restrict__ ensw,
                                             const float* __restrict__ ensb,
                                             float* __restrict__ ws,
                                             float* __restrict__ dout) {
  __shared__ ushort xcat[12800];    // [cc 0..127][s 0..99]
  __shared__ ushort ews[64 * 130];  // [o][cc] padded
  __shared__ ushort obuf[6400];
  __shared__ float red[512];
  int bid = blockIdx.x, tid = threadIdx.x;
  int n = bid >> 4, t0 = (bid & 15) * 8;
  for (int idx = tid; idx < 8192; idx += 256) {
    int o = idx >> 7, cc = idx & 127;
    ews[o * 130 + cc] = f2b(ensw[idx]);
  }
  int o = tid >> 2, sq = tid & 3;
  float eb = ensb[o];
  float lsum = 0.f, lss = 0.f;
  for (int h = 0; h < 2; ++h) {
    int tt0 = t0 + h * 4;
    __syncthreads();
    for (int idx = tid; idx < 12800; idx += 256) {
      int cc = idx / 100, s = idx - cc * 100;
      float val = (cc < 64)
          ? dout[(size_t)n * 204800 + (size_t)cc * 3200 + tt0 * 25 + s]
          : ws[WS_YBUF + (size_t)n * 204800 + (size_t)(cc - 64) * 3200 + tt0 * 25 + s];
      xcat[idx] = f2b(val);
    }
    __syncthreads();
    for (int j5 = 0; j5 < 5; ++j5) {
      float t5[5] = {eb, eb, eb, eb, eb};
      int s0 = sq + 20 * j5;
      for (int cc = 0; cc < 128; ++cc) {
        float w = b2f(ews[o * 130 + cc]);
        const ushort* xr = &xcat[cc * 100 + s0];
#pragma unroll
        for (int q = 0; q < 5; ++q) t5[q] = fmaf(w, b2f(xr[4 * q]), t5[q]);
      }
#pragma unroll
      for (int q = 0; q < 5; ++q) {
        float v = t5[q];
        obuf[o * 100 + s0 + 4 * q] = f2b(v);
        lsum += v; lss += v * v;
      }
    }
    __syncthreads();
    float* ob = dout + (size_t)n * 204800 + (size_t)tt0 * 25;
    for (int idx = tid; idx < 6400; idx += 256) {
      int cc = idx / 100, s = idx - cc * 100;
      ob[cc * 3200 + s] = b2f(obuf[idx]);
    }
  }
  red[tid] = lsum;
  red[256 + tid] = lss;
  __syncthreads();
  if ((tid & 3) == 0) {
    float s = red[tid] + red[tid + 1] + red[tid + 2] + red[tid + 3];
    float ss = red[256 + tid] + red[256 + tid + 1] + red[256 + tid + 2] + red[256 + tid + 3];
    ws[WS_BN2P + (size_t)bid * 128 + o * 2] = s;
    ws[WS_BN2P + (size_t)bid * 128 + o * 2 + 1] = ss;
  }
}

// ============ K9: BN2 reduce ============
__global__ __launch_bounds__(256) void k_bn2(const float* __restrict__ g2,
                                             const float* __restrict__ b2,
                                             float* __restrict__ ws) {
  int tid = threadIdx.x;
  if (tid < 64) {
    float s = 0.f, ss = 0.f;
    for (int b = 0; b < 2048; b++) {
      s += ws[WS_BN2P + (size_t)b * 128 + tid * 2];
      ss += ws[WS_BN2P + (size_t)b * 128 + tid * 2 + 1];
    }
    float mu = s / MTOT;
    float var = ss / MTOT - mu * mu;
    float a2 = g2[tid] * rsqrtf(var + 1e-5f);
    ws[WS_PAR + 384 + tid] = a2;
    ws[WS_PAR + 448 + tid] = b2[tid] - a2 * mu;
  }
}

// ============ K10: final BN2 apply + residual + ReLU (in-place) ============
__global__ __launch_bounds__(256) void k_final(const float* __restrict__ x0,
                                               const float* __restrict__ ws,
                                               float* __restrict__ dout) {
  size_t g = (size_t)blockIdx.x * 256 + threadIdx.x;
  float4 p = reinterpret_cast<const float4*>(dout)[g];
  float4 x = reinterpret_cast<const float4*>(x0)[g];
  int o = (int)((g * 4 / 3200) & 63);
  float a2 = ws[WS_PAR + 384 + o], bc = ws[WS_PAR + 448 + o];
  float4 r;
  r.x = fmaxf(fmaf(a2, p.x, bc) + x.x, 0.f);
  r.y = fmaxf(fmaf(a2, p.y, bc) + x.y, 0.f);
  r.z = fmaxf(fmaf(a2, p.z, bc) + x.z, 0.f);
  r.w = fmaxf(fmaf(a2, p.w, bc) + x.w, 0.f);
  reinterpret_cast<float4*>(dout)[g] = r;
}

extern "C" void kernel_launch(void* const* d_in, const int* in_sizes, int n_in,
                              void* d_out, int out_size, void* d_ws, size_t ws_size,
                              hipStream_t stream) {
  const float* x0    = (const float*)d_in[0];
  const float* DA    = (const float*)d_in[1];
  const float* Ag    = (const float*)d_in[2];
  const float* alpha = (const float*)d_in[3];
  const float* w1    = (const float*)d_in[4];
  const float* b1    = (const float*)d_in[5];
  const float* w2    = (const float*)d_in[6];
  const float* b2    = (const float*)d_in[7];
  const float* w3    = (const float*)d_in[8];
  const float* b3    = (const float*)d_in[9];
  const float* w4    = (const float*)d_in[10];
  const float* b4    = (const float*)d_in[11];
  const float* Lw    = (const float*)d_in[12];
  // d_in[13] Linear_bias: cancels under training-mode BN — unused
  const float* g0    = (const float*)d_in[14];
  const float* b0    = (const float*)d_in[15];
  const float* ensw  = (const float*)d_in[16];
  const float* ensb  = (const float*)d_in[17];
  const float* g2    = (const float*)d_in[18];
  const float* b2n   = (const float*)d_in[19];
  float* out = (float*)d_out;
  float* ws  = (float*)d_ws;

  k_gram<<<256, 256, 0, stream>>>(x0, out + DO_GP);
  k_xm<<<8192, 256, 0, stream>>>(x0, out);
  k_params<<<1, 256, 0, stream>>>(out, DA, Lw, g0, b0, ws);
  k_att<<<384, 256, 0, stream>>>(out, w1, b1, w2, b2, w4, b4, Ag, alpha);
  k_ybr<<<2048, 256, 0, stream>>>(x0, out, w3, b3, ws);
  k_linc<<<2048, 256, 0, stream>>>(x0, ws, out);
  k_ens<<<2048, 256, 0, stream>>>(ensw, ensb, ws, out);
  k_bn2<<<1, 256, 0, stream>>>(g2, b2n, ws);
  k_final<<<25600, 256, 0, stream>>>(x0, ws, out);
}

// Round 3
// 893.069 us; speedup vs baseline: 14.2525x; 3.5437x over previous
//
#include <hip/hip_runtime.h>
#include <cstddef>
#include <cstring>

typedef _Float16 h8 __attribute__((ext_vector_type(8)));
typedef float f4 __attribute__((ext_vector_type(4)));
typedef unsigned int u32;
typedef unsigned short u16;

#define MTOT 409600.0f

// ---- d_out scratch offsets (floats) ----
#define DO_XM  15360000
#define DO_GP  15564800

// ---- ws float offsets ----
#define WS_XBUF 0               // u32[128*64*128*13] = 13,631,488
#define WS_ATT  13631488        // f16 [128][3][64][25][32] (base f16 idx = 2x)
#define WS_ATTB 23461888        // f32 [128][64][25]
#define WS_BN2P 23666688        // f32 [1024][128]
#define WS_NAB  23797760        // f16 [3][8][32][32]
#define WS_CB   23810048        // f16 [64][32]
#define WS_WA   23811072        // f16 [3][64][64]
#define WS_W3   23817216        // f16 [3][64][64]
#define WS_EW   23823360        // f16 [64][128]
#define WS_PAR  23827456        // f32 a2[64], b2c[64]

// f16-unit offsets (2x float offsets)
#define ATT_H 27262976
#define NAB_H 47595520
#define CB_H  47620096
#define WA_H  47622144
#define W3_H  47634432
#define EW_H  47646720

#define LDS_DYN 116736   // XsT[400][64]f16 (51200) + H[64][16][32]f16 (65536)

// ============ K1: Gram partials + M1 (fp32) ============
__global__ __launch_bounds__(256) void k_gram(const float* __restrict__ x0,
                                              float* __restrict__ gp) {
  __shared__ float Xs[64 * 65];
  int b = blockIdx.x, tid = threadIdx.x;
  int n = b >> 1;
  int tv0 = (b & 1) * 1600;
  const float* xb = x0 + (size_t)n * (64 * 3200);
  float g[4][4];
#pragma unroll
  for (int a = 0; a < 4; a++)
#pragma unroll
    for (int bb = 0; bb < 4; bb++) g[a][bb] = 0.f;
  float m1 = 0.f;
  int ci0 = (tid >> 4) * 4, cj0 = (tid & 15) * 4;
  for (int sub = 0; sub < 25; sub++) {
    __syncthreads();
    for (int idx = tid; idx < 4096; idx += 256) {
      int c = idx >> 6, s = idx & 63;
      Xs[c * 65 + s] = xb[c * 3200 + tv0 + sub * 64 + s];
    }
    __syncthreads();
    if (tid < 64) {
      float s = 0.f;
#pragma unroll
      for (int su = 0; su < 64; su++) s += Xs[tid * 65 + su];
      m1 += s;
    }
    for (int s = 0; s < 64; s++) {
      float bv[4];
#pragma unroll
      for (int bb = 0; bb < 4; bb++) bv[bb] = Xs[(cj0 + bb) * 65 + s];
#pragma unroll
      for (int a = 0; a < 4; a++) {
        float av = Xs[(ci0 + a) * 65 + s];
#pragma unroll
        for (int bb = 0; bb < 4; bb++) g[a][bb] += av * bv[bb];
      }
    }
  }
  float* o = gp + (size_t)b * 4160;
#pragma unroll
  for (int a = 0; a < 4; a++)
#pragma unroll
    for (int bb = 0; bb < 4; bb++) o[(ci0 + a) * 64 + (cj0 + bb)] = g[a][bb];
  if (tid < 64) o[4096 + tid] = m1;
}

// ============ K3: xm = mean over T; also zero attB ============
__global__ __launch_bounds__(256) void k_xm(const float* __restrict__ x0,
                                            float* __restrict__ dsc,
                                            float* __restrict__ ws) {
  __shared__ float red[8][32];
  int bid = blockIdx.x;
  int gid = bid * 256 + threadIdx.x;
  if (gid < 204800) ws[WS_ATTB + gid] = 0.f;
  int n = bid >> 6, c = bid & 63;
  int tid = threadIdx.x;
  int tq = tid >> 5, v = tid & 31;
  const float* xb = x0 + (size_t)(n * 64 + c) * 3200;
  float s = 0.f;
  if (v < 25) {
    for (int j = 0; j < 16; j++) s += xb[(tq + 8 * j) * 25 + v];
  }
  red[tq][v] = s;
  __syncthreads();
  if (tq == 0 && v < 25) {
    float tot = 0.f;
#pragma unroll
    for (int q = 0; q < 8; q++) tot += red[q][v];
    dsc[DO_XM + (size_t)(n * 64 + c) * 25 + v] = tot * (1.0f / 128.0f);
  }
}

// ===== K2: Gram->BN1 fold; NAB (padded, f16); WA/W3/EW/CB =====
__global__ __launch_bounds__(256) void k_params(const float* __restrict__ dsc,
                                                const float* __restrict__ DA,
                                                const float* __restrict__ Lw,
                                                const float* __restrict__ g0,
                                                const float* __restrict__ b0,
                                                const float* __restrict__ w3,
                                                const float* __restrict__ ensw,
                                                float* __restrict__ wsF) {
  __shared__ float Gs[4096];
  __shared__ float m1s[64];
  __shared__ float Hh[6144];
  __shared__ float a1s[192];
  __shared__ float b1s[192];
  __shared__ float csn[600];
  int tid = threadIdx.x;
  _Float16* wsH = (_Float16*)wsF;
  const float* gp = dsc + DO_GP;
  // normalized adjacency -> NAB[k][g][w][v] f16, v padded to 32 (zeros)
  for (int col = tid; col < 600; col += 256) {
    int k = col / 200, g = (col / 25) % 8, w = col % 25;
    const float* base = DA + (k * 8 + g) * 625 + w;
    float s = 0.f;
    for (int v = 0; v < 25; v++) s += base[v * 25];
    float inv = 1.0f / (s + 0.001f);
    csn[col] = s * inv;
    _Float16* dst = wsH + NAB_H + (size_t)((k * 8 + g) * 32 + w) * 32;
    for (int v = 0; v < 25; v++) dst[v] = (_Float16)(base[v * 25] * inv);
    for (int v = 25; v < 32; v++) dst[v] = (_Float16)0.f;
  }
  for (int col = tid; col < 168; col += 256) {  // zero pad rows w=25..31
    int kg = col / 7, w = 25 + col % 7;
    _Float16* dst = wsH + NAB_H + (size_t)(kg * 32 + w) * 32;
    for (int v = 0; v < 32; v++) dst[v] = (_Float16)0.f;
  }
  if (tid < 64) {
    float s = 0.f;
    for (int b = 0; b < 256; b++) s += gp[(size_t)b * 4160 + 4096 + tid];
    m1s[tid] = s;
  }
  for (int idx = tid; idx < 4096; idx += 256) {
    float s = 0.f;
    for (int b = 0; b < 256; b++) s += gp[(size_t)b * 4160 + idx];
    Gs[idx] = s;
  }
  __syncthreads();
  float exacc = 0.f;
  for (int p = 0; p < 2; p++) {
    for (int idx = tid; idx < 6144; idx += 256) {
      int cl = idx / 192, d = idx % 192;
      int c = p * 32 + cl;
      float acc = 0.f;
      for (int c2 = 0; c2 < 64; c2++) acc += Gs[c * 64 + c2] * Lw[c2 * 192 + d];
      Hh[cl * 192 + d] = acc;
    }
    __syncthreads();
    if (tid < 192) {
      for (int cl = 0; cl < 32; cl++)
        exacc += Lw[(p * 32 + cl) * 192 + tid] * Hh[cl * 192 + tid];
    }
    __syncthreads();
  }
  if (tid < 192) {
    float mu = 0.f;
    for (int c = 0; c < 64; c++) mu += m1s[c] * Lw[c * 192 + tid];
    mu *= (1.0f / MTOT);
    float ex2 = exacc * (1.0f / MTOT);
    float var = ex2 - mu * mu;
    float a1 = g0[tid] * rsqrtf(var + 1e-5f);
    a1s[tid] = a1;
    b1s[tid] = b0[tid] - a1 * mu;  // Linear_bias cancels in training-mode BN
  }
  __syncthreads();
  for (int idx = tid; idx < 12288; idx += 256) {
    int k = idx >> 12, c = (idx >> 6) & 63, e = idx & 63;
    wsH[WA_H + idx] = (_Float16)(a1s[k * 64 + c] * Lw[e * 192 + k * 64 + c]);
  }
  for (int idx = tid; idx < 12288; idx += 256)
    wsH[W3_H + idx] = (_Float16)w3[idx];
  for (int idx = tid; idx < 8192; idx += 256)
    wsH[EW_H + idx] = (_Float16)ensw[idx];
  for (int idx = tid; idx < 2048; idx += 256) {
    int c = idx >> 5, w = idx & 31;
    float s = 0.f;
    if (w < 25) {
      int g = c & 7;
      for (int k = 0; k < 3; k++) s += b1s[k * 64 + c] * csn[k * 200 + g * 25 + w];
    }
    wsH[CB_H + idx] = (_Float16)s;
  }
}

// ============ K4: attention -> attT f16 [n][i][c][v=w][u pad32] + attB ============
__global__ __launch_bounds__(256) void k_att(const float* __restrict__ dsc,
    const float* __restrict__ w1, const float* __restrict__ b1,
    const float* __restrict__ w2, const float* __restrict__ b2,
    const float* __restrict__ w4, const float* __restrict__ b4,
    const float* __restrict__ Ag, const float* __restrict__ alpha,
    const float* __restrict__ b3, float* __restrict__ wsF) {
  __shared__ float xms[1600];
  __shared__ float x1s[200];
  __shared__ float x2s[200];
  __shared__ float Td[5000];
  int bid = blockIdx.x, tid = threadIdx.x;
  int n = bid / 3, i = bid % 3;
  for (int idx = tid; idx < 1600; idx += 256)
    xms[idx] = dsc[DO_XM + (size_t)n * 1600 + idx];
  __syncthreads();
  for (int idx = tid; idx < 400; idx += 256) {
    int r = (idx % 200) / 25, u = idx % 25;
    const float* wv = (idx < 200 ? w1 : w2) + (i * 8 + r) * 64;
    float acc = (idx < 200 ? b1 : b2)[i * 8 + r];
    for (int c = 0; c < 64; c++) acc += xms[c * 25 + u] * wv[c];
    if (idx < 200) x1s[r * 25 + u] = acc; else x2s[r * 25 + u] = acc;
  }
  __syncthreads();
  for (int idx = tid; idx < 5000; idx += 256) {
    int r = idx / 625, u = (idx % 625) / 25, w = idx % 25;
    Td[idx] = tanhf(x1s[r * 25 + u] - x2s[r * 25 + w]);
  }
  __syncthreads();
  float al = alpha[0];
  u32* attW = (u32*)wsF;
  for (int p = tid; p < 1600; p += 256) {
    int o = p / 25, w = p % 25;
    float w4r[8];
#pragma unroll
    for (int r = 0; r < 8; r++) w4r[r] = w4[(i * 64 + o) * 8 + r];
    float b4v = b4[i * 64 + o];
    const float* AgW = Ag + i * 625 + w;
    float asum = 0.f;
    size_t rowH = (size_t)ATT_H + ((size_t)((n * 3 + i) * 64 + o) * 25 + w) * 32;
    u32* row = attW + rowH / 2;
    for (int up = 0; up < 16; ++up) {
      u32 word = 0;
#pragma unroll
      for (int h = 0; h < 2; ++h) {
        int u = up * 2 + h;
        float v = 0.f;
        if (u < 25) {
          float acc = b4v;
#pragma unroll
          for (int r = 0; r < 8; r++) acc += w4r[r] * Td[r * 625 + u * 25 + w];
          v = al * acc + AgW[u * 25];
          asum += v;
        }
        union { _Float16 hf; u16 b; } cv;
        cv.hf = (_Float16)v;
        word |= ((u32)cv.b) << (16 * h);
      }
      row[up] = word;
    }
    atomicAdd(&wsF[WS_ATTB + (size_t)n * 1600 + p], b3[i * 64 + o] * asum);
  }
}

// ---- shared device helpers for kA/kB ----
__device__ __forceinline__ void stageX(const float* __restrict__ xn, char* sm, int tid) {
  for (int idx = tid; idx < 25600; idx += 512) {
    int c = idx / 400, s = idx % 400;
    float f = xn[c * 3200 + s];
    *(_Float16*)(sm + s * 128 + ((c * 2) ^ ((s & 7) << 4))) = (_Float16)f;
  }
}
__device__ __forceinline__ void zeroHpads(char* sm, int tid) {
  for (int idx = tid; idx < 7168; idx += 512) {
    int c = idx / 112, r = idx % 112;
    int t = r / 7, u = 25 + r % 7;
    int hs = (((t & 3) ^ ((c >> 2) & 3)) << 4);
    *(_Float16*)(sm + 51200 + c * 1024 + t * 64 + ((u * 2) ^ hs)) = (_Float16)0.f;
  }
}
// 64-row GEMM: H[c][t][u] = sum_e A[c][e] * XsT[s][e]
__device__ __forceinline__ void gemm64(const _Float16* __restrict__ Aw, char* sm,
                                       int wid, int lane) {
  int l15 = lane & 15, l4 = lane >> 4;
  int mt = wid & 3, half = wid >> 2;
  h8 a0 = *(const h8*)(Aw + (mt * 16 + l15) * 64 + l4 * 8);
  h8 a1 = *(const h8*)(Aw + (mt * 16 + l15) * 64 + 32 + l4 * 8);
  int nt0 = half * 13, nt1 = 13 + half * 12;
  for (int nt = nt0; nt < nt1; ++nt) {
    int s = nt * 16 + l15;
    int sw = (s & 7) << 4;
    const char* rb = sm + s * 128;
    h8 b0 = *(const h8*)(rb + ((l4 * 16) ^ sw));
    h8 b1 = *(const h8*)(rb + ((64 + l4 * 16) ^ sw));
    f4 acc = {0.f, 0.f, 0.f, 0.f};
    acc = __builtin_amdgcn_mfma_f32_16x16x32_f16(a0, b0, acc, 0, 0, 0);
    acc = __builtin_amdgcn_mfma_f32_16x16x32_f16(a1, b1, acc, 0, 0, 0);
    int t = s / 25, u = s % 25;
#pragma unroll
    for (int q = 0; q < 4; ++q) {
      int c = mt * 16 + l4 * 4 + q;
      int hs = (((t & 3) ^ ((c >> 2) & 3)) << 4);
      *(_Float16*)(sm + 51200 + c * 1024 + t * 64 + ((u * 2) ^ hs)) = (_Float16)acc[q];
    }
  }
}

// ===== kA: Linear GEMM + graph contraction (both MFMA) -> XBUF =====
__global__ __launch_bounds__(512) void kA(const float* __restrict__ x0,
                                          float* ws) {
  extern __shared__ char sm[];
  const _Float16* wsH = (const _Float16*)ws;
  int tid = threadIdx.x, bid = blockIdx.x;
  int lb = (bid & 7) * 128 + (bid >> 3);
  int n = lb >> 3, tile = lb & 7;
  int wid = tid >> 6, lane = tid & 63, l15 = lane & 15, l4 = lane >> 4;
  stageX(x0 + (size_t)n * 204800 + tile * 400, sm, tid);
  zeroHpads(sm, tid);
  __syncthreads();
  f4 accx[8][2];
#pragma unroll
  for (int a = 0; a < 8; a++)
#pragma unroll
    for (int b = 0; b < 2; b++) accx[a][b] = (f4){0.f, 0.f, 0.f, 0.f};
  int g = wid;
  for (int k = 0; k < 3; ++k) {
    gemm64(wsH + WA_H + k * 4096, sm, wid, lane);
    __syncthreads();
#pragma unroll
    for (int mt2 = 0; mt2 < 8; ++mt2) {
      int c = mt2 * 8 + g;
      int hs = (((l15 & 3) ^ ((c >> 2) & 3)) << 4);
      h8 aH = *(const h8*)(sm + 51200 + c * 1024 + l15 * 64 + ((l4 * 16) ^ hs));
#pragma unroll
      for (int nt2 = 0; nt2 < 2; ++nt2) {
        const _Float16* nb = wsH + NAB_H +
            (size_t)((k * 8 + g) * 32 + nt2 * 16 + l15) * 32 + l4 * 8;
        accx[mt2][nt2] = __builtin_amdgcn_mfma_f32_16x16x32_f16(
            aH, *(const h8*)nb, accx[mt2][nt2], 0, 0, 0);
      }
    }
    __syncthreads();
  }
  // scatter xb (+cb) into LDS [c][16][26] f16, then coalesced dump to XBUF
#pragma unroll
  for (int mt2 = 0; mt2 < 8; ++mt2) {
    int c = mt2 * 8 + g;
#pragma unroll
    for (int nt2 = 0; nt2 < 2; ++nt2) {
      int w = nt2 * 16 + l15;
      if (w < 25) {
        float cbv = (float)wsH[CB_H + c * 32 + w];
#pragma unroll
        for (int q = 0; q < 4; ++q) {
          int t = l4 * 4 + q;
          *(_Float16*)(sm + 51200 + (c * 416 + t * 26 + w) * 2) =
              (_Float16)(accx[mt2][nt2][q] + cbv);
        }
      }
    }
  }
  __syncthreads();
  u32* xb = (u32*)ws;
  for (int id = tid; id < 1024; id += 512) {
    int c = id >> 4, t = id & 15;
    const u32* src = (const u32*)(sm + 51200 + (c * 416 + t * 26) * 2);
    u32* dst = xb + ((size_t)(n * 64 + c) * 128 + tile * 16 + t) * 13;
#pragma unroll
    for (int j = 0; j < 13; ++j) dst[j] = src[j];
  }
}

// ===== kB: x3 GEMM + att contraction (MFMA) + ensemble GEMM + BN2 partials =====
__global__ __launch_bounds__(512) void kB(const float* __restrict__ x0,
                                          float* ws,
                                          const float* __restrict__ ensb,
                                          float* __restrict__ dout) {
  extern __shared__ char sm[];
  __shared__ float redS[128];
  __shared__ float attBs[1600];
  const _Float16* wsH = (const _Float16*)ws;
  int tid = threadIdx.x, bid = blockIdx.x;
  int lb = (bid & 7) * 128 + (bid >> 3);
  int n = lb >> 3, tile = lb & 7;
  int wid = tid >> 6, lane = tid & 63, l15 = lane & 15, l4 = lane >> 4;
  if (tid < 128) redS[tid] = 0.f;
  for (int idx = tid; idx < 1600; idx += 512)
    attBs[idx] = ws[WS_ATTB + (size_t)n * 1600 + idx];
  stageX(x0 + (size_t)n * 204800 + tile * 400, sm, tid);
  zeroHpads(sm, tid);
  __syncthreads();
  f4 accy[8][2];
#pragma unroll
  for (int a = 0; a < 8; a++)
#pragma unroll
    for (int b = 0; b < 2; b++) accy[a][b] = (f4){0.f, 0.f, 0.f, 0.f};
  for (int i = 0; i < 3; ++i) {
    gemm64(wsH + W3_H + i * 4096, sm, wid, lane);
    __syncthreads();
#pragma unroll
    for (int mt2 = 0; mt2 < 8; ++mt2) {
      int c = mt2 * 8 + wid;
      int hs = (((l15 & 3) ^ ((c >> 2) & 3)) << 4);
      h8 aX = *(const h8*)(sm + 51200 + c * 1024 + l15 * 64 + ((l4 * 16) ^ hs));
#pragma unroll
      for (int nt2 = 0; nt2 < 2; ++nt2) {
        int v = nt2 * 16 + l15;
        int vc = v < 25 ? v : 0;
        const _Float16* ab = wsH + ATT_H +
            ((size_t)((n * 3 + i) * 64 + c) * 25 + vc) * 32 + l4 * 8;
        accy[mt2][nt2] = __builtin_amdgcn_mfma_f32_16x16x32_f16(
            aX, *(const h8*)ab, accy[mt2][nt2], 0, 0, 0);
      }
    }
    __syncthreads();
  }
  // phase 3: build catT[400][128] f16 (swizzled) at sm+0
#pragma unroll
  for (int mt2 = 0; mt2 < 8; ++mt2) {
    int c = mt2 * 8 + wid;
#pragma unroll
    for (int nt2 = 0; nt2 < 2; ++nt2) {
      int v = nt2 * 16 + l15;
      if (v < 25) {
        float ab = attBs[c * 25 + v];
#pragma unroll
        for (int q = 0; q < 4; ++q) {
          int t = l4 * 4 + q;
          int s = t * 25 + v;
          *(_Float16*)(sm + s * 256 + (((64 + c) * 2) ^ ((s & 7) << 4))) =
              (_Float16)(accy[mt2][nt2][q] + ab);
        }
      }
    }
  }
  const u32* xbg = (const u32*)ws;
  for (int id = tid; id < 1024; id += 512) {
    int c = id >> 4, t = id & 15;
    const u32* src = xbg + ((size_t)(n * 64 + c) * 128 + tile * 16 + t) * 13;
#pragma unroll
    for (int j = 0; j < 13; ++j) {
      u32 w2 = src[j];
      int s0 = t * 25 + 2 * j;
      *(u16*)(sm + s0 * 256 + ((c * 2) ^ ((s0 & 7) << 4))) = (u16)(w2 & 0xffffu);
      if (2 * j + 1 < 25) {
        int s1 = s0 + 1;
        *(u16*)(sm + s1 * 256 + ((c * 2) ^ ((s1 & 7) << 4))) = (u16)(w2 >> 16);
      }
    }
  }
  __syncthreads();
  // ensemble GEMM
  int mt = wid & 3, half = wid >> 2;
  h8 ea[4];
#pragma unroll
  for (int ks = 0; ks < 4; ++ks)
    ea[ks] = *(const h8*)(wsH + EW_H + (mt * 16 + l15) * 128 + ks * 32 + l4 * 8);
  float eb[4];
#pragma unroll
  for (int q = 0; q < 4; ++q) eb[q] = ensb[mt * 16 + l4 * 4 + q];
  float lsum[4] = {0.f, 0.f, 0.f, 0.f}, lss[4] = {0.f, 0.f, 0.f, 0.f};
  int nt0 = half * 13, nt1 = 13 + half * 12;
  for (int nt = nt0; nt < nt1; ++nt) {
    int s = nt * 16 + l15;
    int sw = (s & 7) << 4;
    f4 acc = {0.f, 0.f, 0.f, 0.f};
#pragma unroll
    for (int ks = 0; ks < 4; ++ks) {
      h8 b = *(const h8*)(sm + s * 256 + (((ks * 32 + l4 * 8) * 2) ^ sw));
      acc = __builtin_amdgcn_mfma_f32_16x16x32_f16(ea[ks], b, acc, 0, 0, 0);
    }
    size_t ob = (size_t)n * 204800 + (size_t)tile * 400 + s;
#pragma unroll
    for (int q = 0; q < 4; ++q) {
      int o = mt * 16 + l4 * 4 + q;
      float val = acc[q] + eb[q];
      dout[ob + (size_t)o * 3200] = val;
      lsum[q] += val;
      lss[q] += val * val;
    }
  }
#pragma unroll
  for (int q = 0; q < 4; ++q) {
    int o = mt * 16 + l4 * 4 + q;
    atomicAdd(&redS[o], lsum[q]);
    atomicAdd(&redS[64 + o], lss[q]);
  }
  __syncthreads();
  if (tid < 64) {
    ws[WS_BN2P + (size_t)bid * 128 + tid * 2] = redS[tid];
    ws[WS_BN2P + (size_t)bid * 128 + tid * 2 + 1] = redS[64 + tid];
  }
}

// ============ K9: BN2 reduce ============
__global__ __launch_bounds__(256) void k_bn2(const float* __restrict__ g2,
                                             const float* __restrict__ b2,
                                             float* __restrict__ ws) {
  int tid = threadIdx.x;
  if (tid < 64) {
    float s = 0.f, ss = 0.f;
    for (int b = 0; b < 1024; b++) {
      s += ws[WS_BN2P + (size_t)b * 128 + tid * 2];
      ss += ws[WS_BN2P + (size_t)b * 128 + tid * 2 + 1];
    }
    float mu = s / MTOT;
    float var = ss / MTOT - mu * mu;
    float a2 = g2[tid] * rsqrtf(var + 1e-5f);
    ws[WS_PAR + tid] = a2;
    ws[WS_PAR + 64 + tid] = b2[tid] - a2 * mu;
  }
}

// ============ K10: BN2 apply + residual + ReLU ============
__global__ __launch_bounds__(256) void k_final(const float* __restrict__ x0,
                                               const float* __restrict__ ws,
                                               float* __restrict__ dout) {
  size_t g = (size_t)blockIdx.x * 256 + threadIdx.x;
  float4 p = reinterpret_cast<const float4*>(dout)[g];
  float4 x = reinterpret_cast<const float4*>(x0)[g];
  int o = (int)((g * 4 / 3200) & 63);
  float a2 = ws[WS_PAR + o], bc = ws[WS_PAR + 64 + o];
  float4 r;
  r.x = fmaxf(fmaf(a2, p.x, bc) + x.x, 0.f);
  r.y = fmaxf(fmaf(a2, p.y, bc) + x.y, 0.f);
  r.z = fmaxf(fmaf(a2, p.z, bc) + x.z, 0.f);
  r.w = fmaxf(fmaf(a2, p.w, bc) + x.w, 0.f);
  reinterpret_cast<float4*>(dout)[g] = r;
}

extern "C" void kernel_launch(void* const* d_in, const int* in_sizes, int n_in,
                              void* d_out, int out_size, void* d_ws, size_t ws_size,
                              hipStream_t stream) {
  const float* x0    = (const float*)d_in[0];
  const float* DA    = (const float*)d_in[1];
  const float* Ag    = (const float*)d_in[2];
  const float* alpha = (const float*)d_in[3];
  const float* w1    = (const float*)d_in[4];
  const float* b1    = (const float*)d_in[5];
  const float* w2    = (const float*)d_in[6];
  const float* b2    = (const float*)d_in[7];
  const float* w3    = (const float*)d_in[8];
  const float* b3    = (const float*)d_in[9];
  const float* w4    = (const float*)d_in[10];
  const float* b4    = (const float*)d_in[11];
  const float* Lw    = (const float*)d_in[12];
  // d_in[13] Linear_bias: cancels under training-mode BN — unused
  const float* g0    = (const float*)d_in[14];
  const float* b0    = (const float*)d_in[15];
  const float* ensw  = (const float*)d_in[16];
  const float* ensb  = (const float*)d_in[17];
  const float* g2    = (const float*)d_in[18];
  const float* b2n   = (const float*)d_in[19];
  float* out = (float*)d_out;
  float* ws  = (float*)d_ws;

  hipFuncSetAttribute((const void*)kA, hipFuncAttributeMaxDynamicSharedMemorySize, LDS_DYN);
  hipFuncSetAttribute((const void*)kB, hipFuncAttributeMaxDynamicSharedMemorySize, LDS_DYN);

  k_gram<<<256, 256, 0, stream>>>(x0, out + DO_GP);
  k_xm<<<8192, 256, 0, stream>>>(x0, out, ws);
  k_params<<<1, 256, 0, stream>>>(out, DA, Lw, g0, b0, w3, ensw, ws);
  k_att<<<384, 256, 0, stream>>>(out, w1, b1, w2, b2, w4, b4, Ag, alpha, b3, ws);
  kA<<<1024, 512, LDS_DYN, stream>>>(x0, ws);
  kB<<<1024, 512, LDS_DYN, stream>>>(x0, ws, ensb, out);
  k_bn2<<<1, 256, 0, stream>>>(g2, b2n, ws);
  k_final<<<25600, 256, 0, stream>>>(x0, ws, out);
}

// Round 4
// 685.122 us; speedup vs baseline: 18.5784x; 1.3035x over previous
//
#include <hip/hip_runtime.h>
#include <cstddef>
#include <cstring>

typedef _Float16 h8 __attribute__((ext_vector_type(8)));
typedef float f4 __attribute__((ext_vector_type(4)));
typedef unsigned int u32;
typedef unsigned short u16;

#define MTOT 409600.0f

// ---- d_out scratch offsets (floats) ----
#define DO_XM  15360000
#define DO_GP  15564800
#define DO_GR  16629760   // reduced Gram row [4160]

// ---- ws float offsets ----
#define WS_XBUF 0               // u32[128*64*128*13] = 13,631,488
#define WS_ATT  13631488        // f16 [128][3][64][25][32] (base f16 idx = 2x)
#define WS_ATTB 23461888        // f32 [128][64][25]
#define WS_BN2P 23666688        // f32 [1024][128]
#define WS_NAB  23797760        // f16 [3][8][32][32]
#define WS_CB   23810048        // f16 [64][32]
#define WS_WA   23811072        // f16 [3][64][64]
#define WS_W3   23817216        // f16 [3][64][64]
#define WS_EW   23823360        // f16 [64][128]
#define WS_PAR  23827456        // f32 a2[64], b2c[64]

// f16-unit offsets (2x float offsets)
#define ATT_H 27262976
#define NAB_H 47595520
#define CB_H  47620096
#define WA_H  47622144
#define W3_H  47634432
#define EW_H  47646720

#define LDS_DYN 116736   // XsT[400][64]f16 (51200) + H[64][16][32]f16 (65536)

// ============ K1: Gram partials + M1 (fp32) ============
__global__ __launch_bounds__(256) void k_gram(const float* __restrict__ x0,
                                              float* __restrict__ gp) {
  __shared__ float Xs[64 * 65];
  int b = blockIdx.x, tid = threadIdx.x;
  int n = b >> 1;
  int tv0 = (b & 1) * 1600;
  const float* xb = x0 + (size_t)n * (64 * 3200);
  float g[4][4];
#pragma unroll
  for (int a = 0; a < 4; a++)
#pragma unroll
    for (int bb = 0; bb < 4; bb++) g[a][bb] = 0.f;
  float m1 = 0.f;
  int ci0 = (tid >> 4) * 4, cj0 = (tid & 15) * 4;
  for (int sub = 0; sub < 25; sub++) {
    __syncthreads();
    for (int idx = tid; idx < 4096; idx += 256) {
      int c = idx >> 6, s = idx & 63;
      Xs[c * 65 + s] = xb[c * 3200 + tv0 + sub * 64 + s];
    }
    __syncthreads();
    if (tid < 64) {
      float s = 0.f;
#pragma unroll
      for (int su = 0; su < 64; su++) s += Xs[tid * 65 + su];
      m1 += s;
    }
    for (int s = 0; s < 64; s++) {
      float bv[4];
#pragma unroll
      for (int bb = 0; bb < 4; bb++) bv[bb] = Xs[(cj0 + bb) * 65 + s];
#pragma unroll
      for (int a = 0; a < 4; a++) {
        float av = Xs[(ci0 + a) * 65 + s];
#pragma unroll
        for (int bb = 0; bb < 4; bb++) g[a][bb] += av * bv[bb];
      }
    }
  }
  float* o = gp + (size_t)b * 4160;
#pragma unroll
  for (int a = 0; a < 4; a++)
#pragma unroll
    for (int bb = 0; bb < 4; bb++) o[(ci0 + a) * 64 + (cj0 + bb)] = g[a][bb];
  if (tid < 64) o[4096 + tid] = m1;
}

// ============ K1b: parallel reduce of the 256 Gram partials ============
__global__ __launch_bounds__(256) void k_gred(float* __restrict__ dsc) {
  int idx = blockIdx.x * 256 + threadIdx.x;
  if (idx >= 4160) return;
  const float* gp = dsc + DO_GP;
  float s0 = 0.f, s1 = 0.f, s2 = 0.f, s3 = 0.f;
  for (int b = 0; b < 256; b += 4) {
    s0 += gp[(size_t)b * 4160 + idx];
    s1 += gp[(size_t)(b + 1) * 4160 + idx];
    s2 += gp[(size_t)(b + 2) * 4160 + idx];
    s3 += gp[(size_t)(b + 3) * 4160 + idx];
  }
  dsc[DO_GR + idx] = (s0 + s1) + (s2 + s3);
}

// ============ K3: xm = mean over T; also zero attB ============
__global__ __launch_bounds__(256) void k_xm(const float* __restrict__ x0,
                                            float* __restrict__ dsc,
                                            float* __restrict__ ws) {
  __shared__ float red[8][32];
  int bid = blockIdx.x;
  int gid = bid * 256 + threadIdx.x;
  if (gid < 204800) ws[WS_ATTB + gid] = 0.f;
  int n = bid >> 6, c = bid & 63;
  int tid = threadIdx.x;
  int tq = tid >> 5, v = tid & 31;
  const float* xb = x0 + (size_t)(n * 64 + c) * 3200;
  float s = 0.f;
  if (v < 25) {
    for (int j = 0; j < 16; j++) s += xb[(tq + 8 * j) * 25 + v];
  }
  red[tq][v] = s;
  __syncthreads();
  if (tq == 0 && v < 25) {
    float tot = 0.f;
#pragma unroll
    for (int q = 0; q < 8; q++) tot += red[q][v];
    dsc[DO_XM + (size_t)(n * 64 + c) * 25 + v] = tot * (1.0f / 128.0f);
  }
}

// ===== K2: Gram->BN1 fold; NAB (padded, f16); WA/W3/EW/CB =====
__global__ __launch_bounds__(256) void k_params(const float* __restrict__ dsc,
                                                const float* __restrict__ DA,
                                                const float* __restrict__ Lw,
                                                const float* __restrict__ g0,
                                                const float* __restrict__ b0,
                                                const float* __restrict__ w3,
                                                const float* __restrict__ ensw,
                                                float* __restrict__ wsF) {
  __shared__ float Gs[4096];
  __shared__ float m1s[64];
  __shared__ float Hh[6144];
  __shared__ float a1s[192];
  __shared__ float b1s[192];
  __shared__ float csn[600];
  int tid = threadIdx.x;
  _Float16* wsH = (_Float16*)wsF;
  const float* gr = dsc + DO_GR;
  // normalized adjacency -> NAB[k][g][w][v] f16, v padded to 32 (zeros)
  for (int col = tid; col < 600; col += 256) {
    int k = col / 200, g = (col / 25) % 8, w = col % 25;
    const float* base = DA + (k * 8 + g) * 625 + w;
    float s = 0.f;
    for (int v = 0; v < 25; v++) s += base[v * 25];
    float inv = 1.0f / (s + 0.001f);
    csn[col] = s * inv;
    _Float16* dst = wsH + NAB_H + (size_t)((k * 8 + g) * 32 + w) * 32;
    for (int v = 0; v < 25; v++) dst[v] = (_Float16)(base[v * 25] * inv);
    for (int v = 25; v < 32; v++) dst[v] = (_Float16)0.f;
  }
  for (int col = tid; col < 168; col += 256) {  // zero pad rows w=25..31
    int kg = col / 7, w = 25 + col % 7;
    _Float16* dst = wsH + NAB_H + (size_t)(kg * 32 + w) * 32;
    for (int v = 0; v < 32; v++) dst[v] = (_Float16)0.f;
  }
  if (tid < 64) m1s[tid] = gr[4096 + tid];
  for (int idx = tid; idx < 4096; idx += 256) Gs[idx] = gr[idx];
  __syncthreads();
  float exacc = 0.f;
  for (int p = 0; p < 2; p++) {
    for (int idx = tid; idx < 6144; idx += 256) {
      int cl = idx / 192, d = idx % 192;
      int c = p * 32 + cl;
      float acc = 0.f;
      for (int c2 = 0; c2 < 64; c2++) acc += Gs[c * 64 + c2] * Lw[c2 * 192 + d];
      Hh[cl * 192 + d] = acc;
    }
    __syncthreads();
    if (tid < 192) {
      for (int cl = 0; cl < 32; cl++)
        exacc += Lw[(p * 32 + cl) * 192 + tid] * Hh[cl * 192 + tid];
    }
    __syncthreads();
  }
  if (tid < 192) {
    float mu = 0.f;
    for (int c = 0; c < 64; c++) mu += m1s[c] * Lw[c * 192 + tid];
    mu *= (1.0f / MTOT);
    float ex2 = exacc * (1.0f / MTOT);
    float var = ex2 - mu * mu;
    float a1 = g0[tid] * rsqrtf(var + 1e-5f);
    a1s[tid] = a1;
    b1s[tid] = b0[tid] - a1 * mu;  // Linear_bias cancels in training-mode BN
  }
  __syncthreads();
  for (int idx = tid; idx < 12288; idx += 256) {
    int k = idx >> 12, c = (idx >> 6) & 63, e = idx & 63;
    wsH[WA_H + idx] = (_Float16)(a1s[k * 64 + c] * Lw[e * 192 + k * 64 + c]);
  }
  for (int idx = tid; idx < 12288; idx += 256)
    wsH[W3_H + idx] = (_Float16)w3[idx];
  for (int idx = tid; idx < 8192; idx += 256)
    wsH[EW_H + idx] = (_Float16)ensw[idx];
  for (int idx = tid; idx < 2048; idx += 256) {
    int c = idx >> 5, w = idx & 31;
    float s = 0.f;
    if (w < 25) {
      int g = c & 7;
      for (int k = 0; k < 3; k++) s += b1s[k * 64 + c] * csn[k * 200 + g * 25 + w];
    }
    wsH[CB_H + idx] = (_Float16)s;
  }
}

// ============ K4: attention -> attT f16 [n][i][c][v=w][u pad32] + attB ============
__global__ __launch_bounds__(256) void k_att(const float* __restrict__ dsc,
    const float* __restrict__ w1, const float* __restrict__ b1,
    const float* __restrict__ w2, const float* __restrict__ b2,
    const float* __restrict__ w4, const float* __restrict__ b4,
    const float* __restrict__ Ag, const float* __restrict__ alpha,
    const float* __restrict__ b3, float* __restrict__ wsF) {
  __shared__ float xms[1600];
  __shared__ float x1s[200];
  __shared__ float x2s[200];
  __shared__ float Td[5000];
  int bid = blockIdx.x, tid = threadIdx.x;
  int n = bid / 3, i = bid % 3;
  for (int idx = tid; idx < 1600; idx += 256)
    xms[idx] = dsc[DO_XM + (size_t)n * 1600 + idx];
  __syncthreads();
  for (int idx = tid; idx < 400; idx += 256) {
    int r = (idx % 200) / 25, u = idx % 25;
    const float* wv = (idx < 200 ? w1 : w2) + (i * 8 + r) * 64;
    float acc = (idx < 200 ? b1 : b2)[i * 8 + r];
    for (int c = 0; c < 64; c++) acc += xms[c * 25 + u] * wv[c];
    if (idx < 200) x1s[r * 25 + u] = acc; else x2s[r * 25 + u] = acc;
  }
  __syncthreads();
  for (int idx = tid; idx < 5000; idx += 256) {
    int r = idx / 625, u = (idx % 625) / 25, w = idx % 25;
    Td[idx] = tanhf(x1s[r * 25 + u] - x2s[r * 25 + w]);
  }
  __syncthreads();
  float al = alpha[0];
  u32* attW = (u32*)wsF;
  for (int p = tid; p < 1600; p += 256) {
    int o = p / 25, w = p % 25;
    float w4r[8];
#pragma unroll
    for (int r = 0; r < 8; r++) w4r[r] = w4[(i * 64 + o) * 8 + r];
    float b4v = b4[i * 64 + o];
    const float* AgW = Ag + i * 625 + w;
    float asum = 0.f;
    size_t rowH = (size_t)ATT_H + ((size_t)((n * 3 + i) * 64 + o) * 25 + w) * 32;
    u32* row = attW + rowH / 2;
    for (int up = 0; up < 16; ++up) {
      u32 word = 0;
#pragma unroll
      for (int h = 0; h < 2; ++h) {
        int u = up * 2 + h;
        float v = 0.f;
        if (u < 25) {
          float acc = b4v;
#pragma unroll
          for (int r = 0; r < 8; r++) acc += w4r[r] * Td[r * 625 + u * 25 + w];
          v = al * acc + AgW[u * 25];
          asum += v;
        }
        union { _Float16 hf; u16 b; } cv;
        cv.hf = (_Float16)v;
        word |= ((u32)cv.b) << (16 * h);
      }
      row[up] = word;
    }
    atomicAdd(&wsF[WS_ATTB + (size_t)n * 1600 + p], b3[i * 64 + o] * asum);
  }
}

// ---- shared device helpers for kA/kB ----
__device__ __forceinline__ void stageX(const float* __restrict__ xn, char* sm, int tid) {
  for (int idx = tid; idx < 25600; idx += 512) {
    int c = idx / 400, s = idx % 400;
    float f = xn[c * 3200 + s];
    *(_Float16*)(sm + s * 128 + ((c * 2) ^ ((s & 7) << 4))) = (_Float16)f;
  }
}
__device__ __forceinline__ void zeroHpads(char* sm, int tid) {
  for (int idx = tid; idx < 7168; idx += 512) {
    int c = idx / 112, r = idx % 112;
    int t = r / 7, u = 25 + r % 7;
    int hs = (((t & 3) ^ ((c >> 2) & 3)) << 4);
    *(_Float16*)(sm + 51200 + c * 1024 + t * 64 + ((u * 2) ^ hs)) = (_Float16)0.f;
  }
}
// 64-row GEMM: H[c][t][u] = sum_e A[c][e] * XsT[s][e]
__device__ __forceinline__ void gemm64(const _Float16* __restrict__ Aw, char* sm,
                                       int wid, int lane) {
  int l15 = lane & 15, l4 = lane >> 4;
  int mt = wid & 3, half = wid >> 2;
  h8 a0 = *(const h8*)(Aw + (mt * 16 + l15) * 64 + l4 * 8);
  h8 a1 = *(const h8*)(Aw + (mt * 16 + l15) * 64 + 32 + l4 * 8);
  int nt0 = half * 13, nt1 = 13 + half * 12;
  for (int nt = nt0; nt < nt1; ++nt) {
    int s = nt * 16 + l15;
    int sw = (s & 7) << 4;
    const char* rb = sm + s * 128;
    h8 b0 = *(const h8*)(rb + ((l4 * 16) ^ sw));
    h8 b1 = *(const h8*)(rb + ((64 + l4 * 16) ^ sw));
    f4 acc = {0.f, 0.f, 0.f, 0.f};
    acc = __builtin_amdgcn_mfma_f32_16x16x32_f16(a0, b0, acc, 0, 0, 0);
    acc = __builtin_amdgcn_mfma_f32_16x16x32_f16(a1, b1, acc, 0, 0, 0);
    int t = s / 25, u = s % 25;
#pragma unroll
    for (int q = 0; q < 4; ++q) {
      int c = mt * 16 + l4 * 4 + q;
      int hs = (((t & 3) ^ ((c >> 2) & 3)) << 4);
      *(_Float16*)(sm + 51200 + c * 1024 + t * 64 + ((u * 2) ^ hs)) = (_Float16)acc[q];
    }
  }
}

// ===== kA: Linear GEMM + graph contraction (both MFMA) -> XBUF =====
__global__ __launch_bounds__(512) void kA(const float* __restrict__ x0,
                                          float* ws) {
  extern __shared__ char sm[];
  const _Float16* wsH = (const _Float16*)ws;
  int tid = threadIdx.x, bid = blockIdx.x;
  int lb = (bid & 7) * 128 + (bid >> 3);
  int n = lb >> 3, tile = lb & 7;
  int wid = tid >> 6, lane = tid & 63, l15 = lane & 15, l4 = lane >> 4;
  stageX(x0 + (size_t)n * 204800 + tile * 400, sm, tid);
  zeroHpads(sm, tid);
  __syncthreads();
  f4 accx[8][2];
#pragma unroll
  for (int a = 0; a < 8; a++)
#pragma unroll
    for (int b = 0; b < 2; b++) accx[a][b] = (f4){0.f, 0.f, 0.f, 0.f};
  int g = wid;
  for (int k = 0; k < 3; ++k) {
    gemm64(wsH + WA_H + k * 4096, sm, wid, lane);
    __syncthreads();
#pragma unroll
    for (int mt2 = 0; mt2 < 8; ++mt2) {
      int c = mt2 * 8 + g;
      int hs = (((l15 & 3) ^ ((c >> 2) & 3)) << 4);
      h8 aH = *(const h8*)(sm + 51200 + c * 1024 + l15 * 64 + ((l4 * 16) ^ hs));
#pragma unroll
      for (int nt2 = 0; nt2 < 2; ++nt2) {
        const _Float16* nb = wsH + NAB_H +
            (size_t)((k * 8 + g) * 32 + nt2 * 16 + l15) * 32 + l4 * 8;
        accx[mt2][nt2] = __builtin_amdgcn_mfma_f32_16x16x32_f16(
            aH, *(const h8*)nb, accx[mt2][nt2], 0, 0, 0);
      }
    }
    __syncthreads();
  }
  // scatter xb (+cb) into LDS [c][16][26] f16, then coalesced dump to XBUF
#pragma unroll
  for (int mt2 = 0; mt2 < 8; ++mt2) {
    int c = mt2 * 8 + g;
#pragma unroll
    for (int nt2 = 0; nt2 < 2; ++nt2) {
      int w = nt2 * 16 + l15;
      if (w < 25) {
        float cbv = (float)wsH[CB_H + c * 32 + w];
#pragma unroll
        for (int q = 0; q < 4; ++q) {
          int t = l4 * 4 + q;
          *(_Float16*)(sm + 51200 + (c * 416 + t * 26 + w) * 2) =
              (_Float16)(accx[mt2][nt2][q] + cbv);
        }
      }
    }
  }
  __syncthreads();
  u32* xb = (u32*)ws;
  for (int id = tid; id < 1024; id += 512) {
    int c = id >> 4, t = id & 15;
    const u32* src = (const u32*)(sm + 51200 + (c * 416 + t * 26) * 2);
    u32* dst = xb + ((size_t)(n * 64 + c) * 128 + tile * 16 + t) * 13;
#pragma unroll
    for (int j = 0; j < 13; ++j) dst[j] = src[j];
  }
}

// ===== kB: x3 GEMM + att contraction (MFMA) + ensemble GEMM + BN2 partials =====
__global__ __launch_bounds__(512) void kB(const float* __restrict__ x0,
                                          float* ws,
                                          const float* __restrict__ ensb,
                                          float* __restrict__ dout) {
  extern __shared__ char sm[];
  __shared__ float redS[128];
  __shared__ float attBs[1600];
  const _Float16* wsH = (const _Float16*)ws;
  int tid = threadIdx.x, bid = blockIdx.x;
  int lb = (bid & 7) * 128 + (bid >> 3);
  int n = lb >> 3, tile = lb & 7;
  int wid = tid >> 6, lane = tid & 63, l15 = lane & 15, l4 = lane >> 4;
  if (tid < 128) redS[tid] = 0.f;
  for (int idx = tid; idx < 1600; idx += 512)
    attBs[idx] = ws[WS_ATTB + (size_t)n * 1600 + idx];
  stageX(x0 + (size_t)n * 204800 + tile * 400, sm, tid);
  zeroHpads(sm, tid);
  __syncthreads();
  f4 accy[8][2];
#pragma unroll
  for (int a = 0; a < 8; a++)
#pragma unroll
    for (int b = 0; b < 2; b++) accy[a][b] = (f4){0.f, 0.f, 0.f, 0.f};
  for (int i = 0; i < 3; ++i) {
    gemm64(wsH + W3_H + i * 4096, sm, wid, lane);
    __syncthreads();
#pragma unroll
    for (int mt2 = 0; mt2 < 8; ++mt2) {
      int c = mt2 * 8 + wid;
      int hs = (((l15 & 3) ^ ((c >> 2) & 3)) << 4);
      h8 aX = *(const h8*)(sm + 51200 + c * 1024 + l15 * 64 + ((l4 * 16) ^ hs));
#pragma unroll
      for (int nt2 = 0; nt2 < 2; ++nt2) {
        int v = nt2 * 16 + l15;
        int vc = v < 25 ? v : 0;
        const _Float16* ab = wsH + ATT_H +
            ((size_t)((n * 3 + i) * 64 + c) * 25 + vc) * 32 + l4 * 8;
        accy[mt2][nt2] = __builtin_amdgcn_mfma_f32_16x16x32_f16(
            aX, *(const h8*)ab, accy[mt2][nt2], 0, 0, 0);
      }
    }
    __syncthreads();
  }
  // phase 3: build catT[400][128] f16 (swizzled) at sm+0
#pragma unroll
  for (int mt2 = 0; mt2 < 8; ++mt2) {
    int c = mt2 * 8 + wid;
#pragma unroll
    for (int nt2 = 0; nt2 < 2; ++nt2) {
      int v = nt2 * 16 + l15;
      if (v < 25) {
        float ab = attBs[c * 25 + v];
#pragma unroll
        for (int q = 0; q < 4; ++q) {
          int t = l4 * 4 + q;
          int s = t * 25 + v;
          *(_Float16*)(sm + s * 256 + (((64 + c) * 2) ^ ((s & 7) << 4))) =
              (_Float16)(accy[mt2][nt2][q] + ab);
        }
      }
    }
  }
  const u32* xbg = (const u32*)ws;
  for (int id = tid; id < 1024; id += 512) {
    int c = id >> 4, t = id & 15;
    const u32* src = xbg + ((size_t)(n * 64 + c) * 128 + tile * 16 + t) * 13;
#pragma unroll
    for (int j = 0; j < 13; ++j) {
      u32 w2 = src[j];
      int s0 = t * 25 + 2 * j;
      *(u16*)(sm + s0 * 256 + ((c * 2) ^ ((s0 & 7) << 4))) = (u16)(w2 & 0xffffu);
      if (2 * j + 1 < 25) {
        int s1 = s0 + 1;
        *(u16*)(sm + s1 * 256 + ((c * 2) ^ ((s1 & 7) << 4))) = (u16)(w2 >> 16);
      }
    }
  }
  __syncthreads();
  // ensemble GEMM
  int mt = wid & 3, half = wid >> 2;
  h8 ea[4];
#pragma unroll
  for (int ks = 0; ks < 4; ++ks)
    ea[ks] = *(const h8*)(wsH + EW_H + (mt * 16 + l15) * 128 + ks * 32 + l4 * 8);
  float eb[4];
#pragma unroll
  for (int q = 0; q < 4; ++q) eb[q] = ensb[mt * 16 + l4 * 4 + q];
  float lsum[4] = {0.f, 0.f, 0.f, 0.f}, lss[4] = {0.f, 0.f, 0.f, 0.f};
  int nt0 = half * 13, nt1 = 13 + half * 12;
  for (int nt = nt0; nt < nt1; ++nt) {
    int s = nt * 16 + l15;
    int sw = (s & 7) << 4;
    f4 acc = {0.f, 0.f, 0.f, 0.f};
#pragma unroll
    for (int ks = 0; ks < 4; ++ks) {
      h8 b = *(const h8*)(sm + s * 256 + (((ks * 32 + l4 * 8) * 2) ^ sw));
      acc = __builtin_amdgcn_mfma_f32_16x16x32_f16(ea[ks], b, acc, 0, 0, 0);
    }
    size_t ob = (size_t)n * 204800 + (size_t)tile * 400 + s;
#pragma unroll
    for (int q = 0; q < 4; ++q) {
      int o = mt * 16 + l4 * 4 + q;
      float val = acc[q] + eb[q];
      dout[ob + (size_t)o * 3200] = val;
      lsum[q] += val;
      lss[q] += val * val;
    }
  }
#pragma unroll
  for (int q = 0; q < 4; ++q) {
    int o = mt * 16 + l4 * 4 + q;
    atomicAdd(&redS[o], lsum[q]);
    atomicAdd(&redS[64 + o], lss[q]);
  }
  __syncthreads();
  if (tid < 64) {
    ws[WS_BN2P + (size_t)bid * 128 + tid * 2] = redS[tid];
    ws[WS_BN2P + (size_t)bid * 128 + tid * 2 + 1] = redS[64 + tid];
  }
}

// ============ K9: BN2 reduce ============
__global__ __launch_bounds__(256) void k_bn2(const float* __restrict__ g2,
                                             const float* __restrict__ b2,
                                             float* __restrict__ ws) {
  int tid = threadIdx.x;
  if (tid < 64) {
    float s = 0.f, ss = 0.f;
    for (int b = 0; b < 1024; b++) {
      s += ws[WS_BN2P + (size_t)b * 128 + tid * 2];
      ss += ws[WS_BN2P + (size_t)b * 128 + tid * 2 + 1];
    }
    float mu = s / MTOT;
    float var = ss / MTOT - mu * mu;
    float a2 = g2[tid] * rsqrtf(var + 1e-5f);
    ws[WS_PAR + tid] = a2;
    ws[WS_PAR + 64 + tid] = b2[tid] - a2 * mu;
  }
}

// ============ K10: BN2 apply + residual + ReLU ============
__global__ __launch_bounds__(256) void k_final(const float* __restrict__ x0,
                                               const float* __restrict__ ws,
                                               float* __restrict__ dout) {
  size_t g = (size_t)blockIdx.x * 256 + threadIdx.x;
  float4 p = reinterpret_cast<const float4*>(dout)[g];
  float4 x = reinterpret_cast<const float4*>(x0)[g];
  int o = (int)((g * 4 / 3200) & 63);
  float a2 = ws[WS_PAR + o], bc = ws[WS_PAR + 64 + o];
  float4 r;
  r.x = fmaxf(fmaf(a2, p.x, bc) + x.x, 0.f);
  r.y = fmaxf(fmaf(a2, p.y, bc) + x.y, 0.f);
  r.z = fmaxf(fmaf(a2, p.z, bc) + x.z, 0.f);
  r.w = fmaxf(fmaf(a2, p.w, bc) + x.w, 0.f);
  reinterpret_cast<float4*>(dout)[g] = r;
}

extern "C" void kernel_launch(void* const* d_in, const int* in_sizes, int n_in,
                              void* d_out, int out_size, void* d_ws, size_t ws_size,
                              hipStream_t stream) {
  const float* x0    = (const float*)d_in[0];
  const float* DA    = (const float*)d_in[1];
  const float* Ag    = (const float*)d_in[2];
  const float* alpha = (const float*)d_in[3];
  const float* w1    = (const float*)d_in[4];
  const float* b1    = (const float*)d_in[5];
  const float* w2    = (const float*)d_in[6];
  const float* b2    = (const float*)d_in[7];
  const float* w3    = (const float*)d_in[8];
  const float* b3    = (const float*)d_in[9];
  const float* w4    = (const float*)d_in[10];
  const float* b4    = (const float*)d_in[11];
  const float* Lw    = (const float*)d_in[12];
  // d_in[13] Linear_bias: cancels under training-mode BN — unused
  const float* g0    = (const float*)d_in[14];
  const float* b0    = (const float*)d_in[15];
  const float* ensw  = (const float*)d_in[16];
  const float* ensb  = (const float*)d_in[17];
  const float* g2    = (const float*)d_in[18];
  const float* b2n   = (const float*)d_in[19];
  float* out = (float*)d_out;
  float* ws  = (float*)d_ws;

  hipFuncSetAttribute((const void*)kA, hipFuncAttributeMaxDynamicSharedMemorySize, LDS_DYN);
  hipFuncSetAttribute((const void*)kB, hipFuncAttributeMaxDynamicSharedMemorySize, LDS_DYN);

  k_gram<<<256, 256, 0, stream>>>(x0, out + DO_GP);
  k_gred<<<17, 256, 0, stream>>>(out);
  k_xm<<<8192, 256, 0, stream>>>(x0, out, ws);
  k_params<<<1, 256, 0, stream>>>(out, DA, Lw, g0, b0, w3, ensw, ws);
  k_att<<<384, 256, 0, stream>>>(out, w1, b1, w2, b2, w4, b4, Ag, alpha, b3, ws);
  kA<<<1024, 512, LDS_DYN, stream>>>(x0, ws);
  kB<<<1024, 512, LDS_DYN, stream>>>(x0, ws, ensb, out);
  k_bn2<<<1, 256, 0, stream>>>(g2, b2n, ws);
  k_final<<<25600, 256, 0, stream>>>(x0, ws, out);
}

// Round 5
// 406.997 us; speedup vs baseline: 31.2742x; 1.6834x over previous
//
#include <hip/hip_runtime.h>
#include <cstddef>
#include <cstring>

typedef _Float16 h8 __attribute__((ext_vector_type(8)));
typedef _Float16 h4v __attribute__((ext_vector_type(4)));
typedef float f4 __attribute__((ext_vector_type(4)));
typedef unsigned int u32;
typedef unsigned short u16;

#define MTOT 409600.0f

// ---- d_out scratch offsets (floats) ----
#define DO_XM  15360000            // [128][64][25] = 204,800
#define DO_GP  15564800            // [256][4096] = 1,048,576
#define DO_GR  16613376            // reduced Gram [4096] + M1 [64]

// ---- ws float offsets ----
#define WS_XBUF 0               // u32[128*64*128*13] = 13,631,488
#define WS_ATT  13631488        // f16 [128][3][64][25][32]
#define WS_ATTB 23461888        // f32 [128][64][25]
#define WS_BN2P 23666688        // f32 [1024][128]
#define WS_PAR  23827456        // f32 a2[64] b2c[64] a1[192] b1c[192] = 512
#define WS_CSN  23828000        // f32 [600]

// f16-unit offsets (2x float offsets)
#define ATT_H 27262976
#define NAB_H 47595520          // f16 [3][8][32][32]
#define CB_H  47620096          // f16 [64][32]
#define WA_H  47622144          // f16 [3][64][64]
#define W3_H  47634432          // f16 [3][64][64]
#define EW_H  47646720          // f16 [64][128]

#define LDS_DYN 116736   // XsT[400][64]f16 (51200) + H[64][16][32]f16 (65536)

// ============ K1: Gram partials via MFMA (f16 in, f32 acc) ============
// grid 256 = (n, s-half); block 512 (8 waves); G_part[bid][64][64]
__global__ __launch_bounds__(512) void k_gram(const float* __restrict__ x0,
                                              float* __restrict__ gp) {
  __shared__ _Float16 Xs[64 * 128];  // 16 KB, row=256B, XOR-swizzled
  char* smb = (char*)Xs;
  int bid = blockIdx.x, tid = threadIdx.x;
  int n = bid >> 1, sh = bid & 1;
  int base = sh * 1536;
  int niter = sh ? 13 : 12;          // 1536 + 1664 = 3200
  const float* xb = x0 + (size_t)n * 204800;
  int wid = tid >> 6, lane = tid & 63, l15 = lane & 15, l4 = lane >> 4;
  int ca = (wid & 3) * 16;
  int jb0 = (wid >> 2) * 2;
  f4 acc[2] = {{0.f, 0.f, 0.f, 0.f}, {0.f, 0.f, 0.f, 0.f}};
  int sc = tid >> 3, scol = (tid & 7) * 16;
  int swz = (sc & 7) << 4;
  for (int it = 0; it < niter; ++it) {
    int s0 = base + it * 128;
    __syncthreads();
    const float* src = xb + sc * 3200 + s0 + scol;
#pragma unroll
    for (int j = 0; j < 4; ++j) {
      float4 f = *(const float4*)(src + j * 4);
      h4v hv = {(_Float16)f.x, (_Float16)f.y, (_Float16)f.z, (_Float16)f.w};
      *(h4v*)(smb + sc * 256 + (((scol + j * 4) * 2) ^ swz)) = hv;
    }
    __syncthreads();
#pragma unroll
    for (int kk = 0; kk < 4; ++kk) {
      int kb = kk * 64 + l4 * 16;
      int arow = ca + l15;
      h8 af = *(const h8*)(smb + arow * 256 + (kb ^ ((arow & 7) << 4)));
#pragma unroll
      for (int j = 0; j < 2; ++j) {
        int brow = (jb0 + j) * 16 + l15;
        h8 bf = *(const h8*)(smb + brow * 256 + (kb ^ ((brow & 7) << 4)));
        acc[j] = __builtin_amdgcn_mfma_f32_16x16x32_f16(af, bf, acc[j], 0, 0, 0);
      }
    }
  }
  float* o = gp + (size_t)bid * 4096;
#pragma unroll
  for (int j = 0; j < 2; ++j)
#pragma unroll
    for (int q = 0; q < 4; ++q)
      o[(ca + l4 * 4 + q) * 64 + (jb0 + j) * 16 + l15] = acc[j][q];
}

// ============ K1b: reduce 256 Gram partials + M1 from xm ============
__global__ __launch_bounds__(256) void k_gred(float* __restrict__ dsc) {
  int bid = blockIdx.x, tid = threadIdx.x;
  if (bid < 16) {
    int idx = bid * 256 + tid;
    const float* gp = dsc + DO_GP;
    float s0 = 0.f, s1 = 0.f, s2 = 0.f, s3 = 0.f;
    for (int b = 0; b < 256; b += 4) {
      s0 += gp[(size_t)b * 4096 + idx];
      s1 += gp[(size_t)(b + 1) * 4096 + idx];
      s2 += gp[(size_t)(b + 2) * 4096 + idx];
      s3 += gp[(size_t)(b + 3) * 4096 + idx];
    }
    dsc[DO_GR + idx] = (s0 + s1) + (s2 + s3);
  } else {
    __shared__ float red[64][5];
    int c = tid >> 2, j = tid & 3;
    float s = 0.f;
    for (int nn = j; nn < 128; nn += 4) {
      const float* xmp = dsc + DO_XM + (size_t)(nn * 64 + c) * 25;
      for (int v = 0; v < 25; ++v) s += xmp[v];
    }
    red[c][j] = s;
    __syncthreads();
    if (j == 0)
      dsc[DO_GR + 4096 + c] = 128.f * (red[c][0] + red[c][1] + red[c][2] + red[c][3]);
  }
}

// ============ K3: xm = mean over T; also zero attB ============
__global__ __launch_bounds__(256) void k_xm(const float* __restrict__ x0,
                                            float* __restrict__ dsc,
                                            float* __restrict__ ws) {
  __shared__ float red[8][32];
  int bid = blockIdx.x;
  int gid = bid * 256 + threadIdx.x;
  if (gid < 204800) ws[WS_ATTB + gid] = 0.f;
  int n = bid >> 6, c = bid & 63;
  int tid = threadIdx.x;
  int tq = tid >> 5, v = tid & 31;
  const float* xb = x0 + (size_t)(n * 64 + c) * 3200;
  float s = 0.f;
  if (v < 25) {
    for (int j = 0; j < 16; j++) s += xb[(tq + 8 * j) * 25 + v];
  }
  red[tq][v] = s;
  __syncthreads();
  if (tq == 0 && v < 25) {
    float tot = 0.f;
#pragma unroll
    for (int q = 0; q < 8; q++) tot += red[q][v];
    dsc[DO_XM + (size_t)(n * 64 + c) * 25 + v] = tot * (1.0f / 128.0f);
  }
}

// ===== K2a: parallel prep — norm_A->NAB f16 + csn; W3/EW f16 copies =====
__global__ __launch_bounds__(256) void k_prep(const float* __restrict__ DA,
                                              const float* __restrict__ w3,
                                              const float* __restrict__ ensw,
                                              float* __restrict__ wsF) {
  int bid = blockIdx.x, tid = threadIdx.x;
  _Float16* wsH = (_Float16*)wsF;
  if (bid < 3) {
    if (tid < 200) {
      int k = bid, g = tid / 25, w = tid % 25;
      const float* base = DA + (k * 8 + g) * 625 + w;
      float s = 0.f;
      for (int v = 0; v < 25; v++) s += base[v * 25];
      float inv = 1.0f / (s + 0.001f);
      wsF[WS_CSN + k * 200 + g * 25 + w] = s * inv;
      _Float16* dst = wsH + NAB_H + (size_t)((k * 8 + g) * 32 + w) * 32;
      for (int v = 0; v < 25; v++) dst[v] = (_Float16)(base[v * 25] * inv);
      for (int v = 25; v < 32; v++) dst[v] = (_Float16)0.f;
    }
  } else if (bid == 3) {
    for (int idx = tid; idx < 5376; idx += 256) {  // pad rows w=25..31
      int kg = idx / 224, r = idx % 224;
      int w = 25 + r / 32, v = r & 31;
      wsH[NAB_H + (size_t)(kg * 32 + w) * 32 + v] = (_Float16)0.f;
    }
  } else if (bid < 12) {
    int i0 = (bid - 4) * 1536;
    for (int i = tid; i < 1536; i += 256)
      wsH[W3_H + i0 + i] = (_Float16)w3[i0 + i];
  } else {
    int i0 = (bid - 12) * 2048;
    for (int i = tid; i < 2048; i += 256)
      wsH[EW_H + i0 + i] = (_Float16)ensw[i0 + i];
  }
}

// ===== K2b: BN1 stats (y^T G y per d) + folded WA rows =====
__global__ __launch_bounds__(256) void k_bnstat(const float* __restrict__ dsc,
                                                const float* __restrict__ Lw,
                                                const float* __restrict__ g0,
                                                const float* __restrict__ b0,
                                                float* __restrict__ wsF) {
  __shared__ float Gsh[64 * 66];
  __shared__ float Ly[64][17];
  __shared__ float part[16][17];
  __shared__ float a1L[16];
  int bid = blockIdx.x, tid = threadIdx.x;
  int d0 = bid * 16, dl = tid >> 4, r = tid & 15, d = d0 + dl;
  for (int idx = tid; idx < 4096; idx += 256)
    Gsh[(idx >> 6) * 66 + (idx & 63)] = dsc[DO_GR + idx];
  for (int idx = tid; idx < 1024; idx += 256)
    Ly[idx >> 4][idx & 15] = Lw[(idx >> 4) * 192 + d0 + (idx & 15)];
  __syncthreads();
  float acc = 0.f;
#pragma unroll
  for (int cc = 0; cc < 4; ++cc) {
    int c = r * 4 + cc;
    float h = 0.f;
    for (int c2 = 0; c2 < 64; ++c2) h += Gsh[c * 66 + c2] * Ly[c2][dl];
    acc += Ly[c][dl] * h;
  }
  part[dl][r] = acc;
  __syncthreads();
  if (r == 0) {
    float ex2 = 0.f;
#pragma unroll
    for (int i = 0; i < 16; ++i) ex2 += part[dl][i];
    ex2 *= (1.0f / MTOT);
    float mu = 0.f;
    for (int c = 0; c < 64; ++c) mu += dsc[DO_GR + 4096 + c] * Ly[c][dl];
    mu *= (1.0f / MTOT);
    float var = ex2 - mu * mu;
    float a1 = g0[d] * rsqrtf(var + 1e-5f);
    float b1c = b0[d] - a1 * mu;  // Linear_bias cancels in training-mode BN
    wsF[WS_PAR + 128 + d] = a1;
    wsF[WS_PAR + 320 + d] = b1c;
    a1L[dl] = a1;
  }
  __syncthreads();
  _Float16* wsH = (_Float16*)wsF;
  int k = d >> 6, cg = d & 63;
  float a1v = a1L[dl];
#pragma unroll
  for (int j = 0; j < 4; ++j) {
    int e = r * 4 + j;
    wsH[WA_H + k * 4096 + cg * 64 + e] = (_Float16)(a1v * Lw[e * 192 + d]);
  }
}

// ===== K2c: cb[c][w] from b1c and csn =====
__global__ __launch_bounds__(256) void k_cb(float* __restrict__ wsF) {
  int tid = threadIdx.x;
  _Float16* wsH = (_Float16*)wsF;
  for (int idx = tid; idx < 2048; idx += 256) {
    int c = idx >> 5, w = idx & 31;
    float s = 0.f;
    if (w < 25) {
      int g = c & 7;
      for (int k = 0; k < 3; ++k)
        s += wsF[WS_PAR + 320 + k * 64 + c] * wsF[WS_CSN + k * 200 + g * 25 + w];
    }
    wsH[CB_H + idx] = (_Float16)s;
  }
}

// ============ K4: attention -> attT f16 [n][i][c][v=w][u pad32] + attB ============
__global__ __launch_bounds__(256) void k_att(const float* __restrict__ dsc,
    const float* __restrict__ w1, const float* __restrict__ b1,
    const float* __restrict__ w2, const float* __restrict__ b2,
    const float* __restrict__ w4, const float* __restrict__ b4,
    const float* __restrict__ Ag, const float* __restrict__ alpha,
    const float* __restrict__ b3, float* __restrict__ wsF) {
  __shared__ float xms[1600];
  __shared__ float x1s[200];
  __shared__ float x2s[200];
  __shared__ float Td[5000];
  int bid = blockIdx.x, tid = threadIdx.x;
  int n = bid / 3, i = bid % 3;
  for (int idx = tid; idx < 1600; idx += 256)
    xms[idx] = dsc[DO_XM + (size_t)n * 1600 + idx];
  __syncthreads();
  for (int idx = tid; idx < 400; idx += 256) {
    int r = (idx % 200) / 25, u = idx % 25;
    const float* wv = (idx < 200 ? w1 : w2) + (i * 8 + r) * 64;
    float acc = (idx < 200 ? b1 : b2)[i * 8 + r];
    for (int c = 0; c < 64; c++) acc += xms[c * 25 + u] * wv[c];
    if (idx < 200) x1s[r * 25 + u] = acc; else x2s[r * 25 + u] = acc;
  }
  __syncthreads();
  for (int idx = tid; idx < 5000; idx += 256) {
    int r = idx / 625, u = (idx % 625) / 25, w = idx % 25;
    Td[idx] = tanhf(x1s[r * 25 + u] - x2s[r * 25 + w]);
  }
  __syncthreads();
  float al = alpha[0];
  u32* attW = (u32*)wsF;
  for (int p = tid; p < 1600; p += 256) {
    int o = p / 25, w = p % 25;
    float w4r[8];
#pragma unroll
    for (int r = 0; r < 8; r++) w4r[r] = w4[(i * 64 + o) * 8 + r];
    float b4v = b4[i * 64 + o];
    const float* AgW = Ag + i * 625 + w;
    float asum = 0.f;
    size_t rowH = (size_t)ATT_H + ((size_t)((n * 3 + i) * 64 + o) * 25 + w) * 32;
    u32* row = attW + rowH / 2;
    for (int up = 0; up < 16; ++up) {
      u32 word = 0;
#pragma unroll
      for (int h = 0; h < 2; ++h) {
        int u = up * 2 + h;
        float v = 0.f;
        if (u < 25) {
          float acc = b4v;
#pragma unroll
          for (int r = 0; r < 8; r++) acc += w4r[r] * Td[r * 625 + u * 25 + w];
          v = al * acc + AgW[u * 25];
          asum += v;
        }
        union { _Float16 hf; u16 b; } cv;
        cv.hf = (_Float16)v;
        word |= ((u32)cv.b) << (16 * h);
      }
      row[up] = word;
    }
    atomicAdd(&wsF[WS_ATTB + (size_t)n * 1600 + p], b3[i * 64 + o] * asum);
  }
}

// ---- shared device helpers for kA/kB ----
__device__ __forceinline__ void stageX(const float* __restrict__ xn, char* sm, int tid) {
  for (int idx = tid; idx < 25600; idx += 512) {
    int c = idx / 400, s = idx % 400;
    float f = xn[c * 3200 + s];
    *(_Float16*)(sm + s * 128 + ((c * 2) ^ ((s & 7) << 4))) = (_Float16)f;
  }
}
__device__ __forceinline__ void zeroHpads(char* sm, int tid) {
  for (int idx = tid; idx < 7168; idx += 512) {
    int c = idx / 112, r = idx % 112;
    int t = r / 7, u = 25 + r % 7;
    int hs = (((t & 3) ^ ((c >> 2) & 3)) << 4);
    *(_Float16*)(sm + 51200 + c * 1024 + t * 64 + ((u * 2) ^ hs)) = (_Float16)0.f;
  }
}
// 64-row GEMM: H[c][t][u] = sum_e A[c][e] * XsT[s][e]
__device__ __forceinline__ void gemm64(const _Float16* __restrict__ Aw, char* sm,
                                       int wid, int lane) {
  int l15 = lane & 15, l4 = lane >> 4;
  int mt = wid & 3, half = wid >> 2;
  h8 a0 = *(const h8*)(Aw + (mt * 16 + l15) * 64 + l4 * 8);
  h8 a1 = *(const h8*)(Aw + (mt * 16 + l15) * 64 + 32 + l4 * 8);
  int nt0 = half * 13, nt1 = 13 + half * 12;
  for (int nt = nt0; nt < nt1; ++nt) {
    int s = nt * 16 + l15;
    int sw = (s & 7) << 4;
    const char* rb = sm + s * 128;
    h8 b0 = *(const h8*)(rb + ((l4 * 16) ^ sw));
    h8 b1 = *(const h8*)(rb + ((64 + l4 * 16) ^ sw));
    f4 acc = {0.f, 0.f, 0.f, 0.f};
    acc = __builtin_amdgcn_mfma_f32_16x16x32_f16(a0, b0, acc, 0, 0, 0);
    acc = __builtin_amdgcn_mfma_f32_16x16x32_f16(a1, b1, acc, 0, 0, 0);
    int t = s / 25, u = s % 25;
#pragma unroll
    for (int q = 0; q < 4; ++q) {
      int c = mt * 16 + l4 * 4 + q;
      int hs = (((t & 3) ^ ((c >> 2) & 3)) << 4);
      *(_Float16*)(sm + 51200 + c * 1024 + t * 64 + ((u * 2) ^ hs)) = (_Float16)acc[q];
    }
  }
}

// ===== kA: Linear GEMM + graph contraction (both MFMA) -> XBUF =====
__global__ __launch_bounds__(512) void kA(const float* __restrict__ x0,
                                          float* ws) {
  extern __shared__ char sm[];
  const _Float16* wsH = (const _Float16*)ws;
  int tid = threadIdx.x, bid = blockIdx.x;
  int lb = (bid & 7) * 128 + (bid >> 3);
  int n = lb >> 3, tile = lb & 7;
  int wid = tid >> 6, lane = tid & 63, l15 = lane & 15, l4 = lane >> 4;
  stageX(x0 + (size_t)n * 204800 + tile * 400, sm, tid);
  zeroHpads(sm, tid);
  __syncthreads();
  f4 accx[8][2];
#pragma unroll
  for (int a = 0; a < 8; a++)
#pragma unroll
    for (int b = 0; b < 2; b++) accx[a][b] = (f4){0.f, 0.f, 0.f, 0.f};
  int g = wid;
  for (int k = 0; k < 3; ++k) {
    gemm64(wsH + WA_H + k * 4096, sm, wid, lane);
    __syncthreads();
#pragma unroll
    for (int mt2 = 0; mt2 < 8; ++mt2) {
      int c = mt2 * 8 + g;
      int hs = (((l15 & 3) ^ ((c >> 2) & 3)) << 4);
      h8 aH = *(const h8*)(sm + 51200 + c * 1024 + l15 * 64 + ((l4 * 16) ^ hs));
#pragma unroll
      for (int nt2 = 0; nt2 < 2; ++nt2) {
        const _Float16* nb = wsH + NAB_H +
            (size_t)((k * 8 + g) * 32 + nt2 * 16 + l15) * 32 + l4 * 8;
        accx[mt2][nt2] = __builtin_amdgcn_mfma_f32_16x16x32_f16(
            aH, *(const h8*)nb, accx[mt2][nt2], 0, 0, 0);
      }
    }
    __syncthreads();
  }
#pragma unroll
  for (int mt2 = 0; mt2 < 8; ++mt2) {
    int c = mt2 * 8 + g;
#pragma unroll
    for (int nt2 = 0; nt2 < 2; ++nt2) {
      int w = nt2 * 16 + l15;
      if (w < 25) {
        float cbv = (float)wsH[CB_H + c * 32 + w];
#pragma unroll
        for (int q = 0; q < 4; ++q) {
          int t = l4 * 4 + q;
          *(_Float16*)(sm + 51200 + (c * 416 + t * 26 + w) * 2) =
              (_Float16)(accx[mt2][nt2][q] + cbv);
        }
      }
    }
  }
  __syncthreads();
  u32* xb = (u32*)ws;
  for (int id = tid; id < 1024; id += 512) {
    int c = id >> 4, t = id & 15;
    const u32* src = (const u32*)(sm + 51200 + (c * 416 + t * 26) * 2);
    u32* dst = xb + ((size_t)(n * 64 + c) * 128 + tile * 16 + t) * 13;
#pragma unroll
    for (int j = 0; j < 13; ++j) dst[j] = src[j];
  }
}

// ===== kB: x3 GEMM + att contraction (MFMA) + ensemble GEMM + BN2 partials =====
__global__ __launch_bounds__(512) void kB(const float* __restrict__ x0,
                                          float* ws,
                                          const float* __restrict__ ensb,
                                          float* __restrict__ dout) {
  extern __shared__ char sm[];
  __shared__ float redS[128];
  __shared__ float attBs[1600];
  const _Float16* wsH = (const _Float16*)ws;
  int tid = threadIdx.x, bid = blockIdx.x;
  int lb = (bid & 7) * 128 + (bid >> 3);
  int n = lb >> 3, tile = lb & 7;
  int wid = tid >> 6, lane = tid & 63, l15 = lane & 15, l4 = lane >> 4;
  if (tid < 128) redS[tid] = 0.f;
  for (int idx = tid; idx < 1600; idx += 512)
    attBs[idx] = ws[WS_ATTB + (size_t)n * 1600 + idx];
  stageX(x0 + (size_t)n * 204800 + tile * 400, sm, tid);
  zeroHpads(sm, tid);
  __syncthreads();
  f4 accy[8][2];
#pragma unroll
  for (int a = 0; a < 8; a++)
#pragma unroll
    for (int b = 0; b < 2; b++) accy[a][b] = (f4){0.f, 0.f, 0.f, 0.f};
  for (int i = 0; i < 3; ++i) {
    gemm64(wsH + W3_H + i * 4096, sm, wid, lane);
    __syncthreads();
#pragma unroll
    for (int mt2 = 0; mt2 < 8; ++mt2) {
      int c = mt2 * 8 + wid;
      int hs = (((l15 & 3) ^ ((c >> 2) & 3)) << 4);
      h8 aX = *(const h8*)(sm + 51200 + c * 1024 + l15 * 64 + ((l4 * 16) ^ hs));
#pragma unroll
      for (int nt2 = 0; nt2 < 2; ++nt2) {
        int v = nt2 * 16 + l15;
        int vc = v < 25 ? v : 0;
        const _Float16* ab = wsH + ATT_H +
            ((size_t)((n * 3 + i) * 64 + c) * 25 + vc) * 32 + l4 * 8;
        accy[mt2][nt2] = __builtin_amdgcn_mfma_f32_16x16x32_f16(
            aX, *(const h8*)ab, accy[mt2][nt2], 0, 0, 0);
      }
    }
    __syncthreads();
  }
#pragma unroll
  for (int mt2 = 0; mt2 < 8; ++mt2) {
    int c = mt2 * 8 + wid;
#pragma unroll
    for (int nt2 = 0; nt2 < 2; ++nt2) {
      int v = nt2 * 16 + l15;
      if (v < 25) {
        float ab = attBs[c * 25 + v];
#pragma unroll
        for (int q = 0; q < 4; ++q) {
          int t = l4 * 4 + q;
          int s = t * 25 + v;
          *(_Float16*)(sm + s * 256 + (((64 + c) * 2) ^ ((s & 7) << 4))) =
              (_Float16)(accy[mt2][nt2][q] + ab);
        }
      }
    }
  }
  const u32* xbg = (const u32*)ws;
  for (int id = tid; id < 1024; id += 512) {
    int c = id >> 4, t = id & 15;
    const u32* src = xbg + ((size_t)(n * 64 + c) * 128 + tile * 16 + t) * 13;
#pragma unroll
    for (int j = 0; j < 13; ++j) {
      u32 w2 = src[j];
      int s0 = t * 25 + 2 * j;
      *(u16*)(sm + s0 * 256 + ((c * 2) ^ ((s0 & 7) << 4))) = (u16)(w2 & 0xffffu);
      if (2 * j + 1 < 25) {
        int s1 = s0 + 1;
        *(u16*)(sm + s1 * 256 + ((c * 2) ^ ((s1 & 7) << 4))) = (u16)(w2 >> 16);
      }
    }
  }
  __syncthreads();
  int mt = wid & 3, half = wid >> 2;
  h8 ea[4];
#pragma unroll
  for (int ks = 0; ks < 4; ++ks)
    ea[ks] = *(const h8*)(wsH + EW_H + (mt * 16 + l15) * 128 + ks * 32 + l4 * 8);
  float eb[4];
#pragma unroll
  for (int q = 0; q < 4; ++q) eb[q] = ensb[mt * 16 + l4 * 4 + q];
  float lsum[4] = {0.f, 0.f, 0.f, 0.f}, lss[4] = {0.f, 0.f, 0.f, 0.f};
  int nt0 = half * 13, nt1 = 13 + half * 12;
  for (int nt = nt0; nt < nt1; ++nt) {
    int s = nt * 16 + l15;
    int sw = (s & 7) << 4;
    f4 acc = {0.f, 0.f, 0.f, 0.f};
#pragma unroll
    for (int ks = 0; ks < 4; ++ks) {
      h8 b = *(const h8*)(sm + s * 256 + (((ks * 32 + l4 * 8) * 2) ^ sw));
      acc = __builtin_amdgcn_mfma_f32_16x16x32_f16(ea[ks], b, acc, 0, 0, 0);
    }
    size_t ob = (size_t)n * 204800 + (size_t)tile * 400 + s;
#pragma unroll
    for (int q = 0; q < 4; ++q) {
      int o = mt * 16 + l4 * 4 + q;
      float val = acc[q] + eb[q];
      dout[ob + (size_t)o * 3200] = val;
      lsum[q] += val;
      lss[q] += val * val;
    }
  }
#pragma unroll
  for (int q = 0; q < 4; ++q) {
    int o = mt * 16 + l4 * 4 + q;
    atomicAdd(&redS[o], lsum[q]);
    atomicAdd(&redS[64 + o], lss[q]);
  }
  __syncthreads();
  if (tid < 64) {
    ws[WS_BN2P + (size_t)bid * 128 + tid * 2] = redS[tid];
    ws[WS_BN2P + (size_t)bid * 128 + tid * 2 + 1] = redS[64 + tid];
  }
}

// ============ K9: BN2 reduce (parallel, one block per channel) ============
__global__ __launch_bounds__(256) void k_bn2(const float* __restrict__ g2,
                                             const float* __restrict__ b2,
                                             float* __restrict__ ws) {
  __shared__ float rs[256], rss[256];
  int o = blockIdx.x, tid = threadIdx.x;
  float s = 0.f, ss = 0.f;
  for (int b = tid; b < 1024; b += 256) {
    s += ws[WS_BN2P + (size_t)b * 128 + o * 2];
    ss += ws[WS_BN2P + (size_t)b * 128 + o * 2 + 1];
  }
  rs[tid] = s; rss[tid] = ss;
  __syncthreads();
  for (int st = 128; st > 0; st >>= 1) {
    if (tid < st) { rs[tid] += rs[tid + st]; rss[tid] += rss[tid + st]; }
    __syncthreads();
  }
  if (tid == 0) {
    float mu = rs[0] / MTOT;
    float var = rss[0] / MTOT - mu * mu;
    float a2 = g2[o] * rsqrtf(var + 1e-5f);
    ws[WS_PAR + o] = a2;
    ws[WS_PAR + 64 + o] = b2[o] - a2 * mu;
  }
}

// ============ K10: BN2 apply + residual + ReLU ============
__global__ __launch_bounds__(256) void k_final(const float* __restrict__ x0,
                                               const float* __restrict__ ws,
                                               float* __restrict__ dout) {
  size_t g = (size_t)blockIdx.x * 256 + threadIdx.x;
  float4 p = reinterpret_cast<const float4*>(dout)[g];
  float4 x = reinterpret_cast<const float4*>(x0)[g];
  int o = (int)((g * 4 / 3200) & 63);
  float a2 = ws[WS_PAR + o], bc = ws[WS_PAR + 64 + o];
  float4 r;
  r.x = fmaxf(fmaf(a2, p.x, bc) + x.x, 0.f);
  r.y = fmaxf(fmaf(a2, p.y, bc) + x.y, 0.f);
  r.z = fmaxf(fmaf(a2, p.z, bc) + x.z, 0.f);
  r.w = fmaxf(fmaf(a2, p.w, bc) + x.w, 0.f);
  reinterpret_cast<float4*>(dout)[g] = r;
}

extern "C" void kernel_launch(void* const* d_in, const int* in_sizes, int n_in,
                              void* d_out, int out_size, void* d_ws, size_t ws_size,
                              hipStream_t stream) {
  const float* x0    = (const float*)d_in[0];
  const float* DA    = (const float*)d_in[1];
  const float* Ag    = (const float*)d_in[2];
  const float* alpha = (const float*)d_in[3];
  const float* w1    = (const float*)d_in[4];
  const float* b1    = (const float*)d_in[5];
  const float* w2    = (const float*)d_in[6];
  const float* b2    = (const float*)d_in[7];
  const float* w3    = (const float*)d_in[8];
  const float* b3    = (const float*)d_in[9];
  const float* w4    = (const float*)d_in[10];
  const float* b4    = (const float*)d_in[11];
  const float* Lw    = (const float*)d_in[12];
  // d_in[13] Linear_bias: cancels under training-mode BN — unused
  const float* g0    = (const float*)d_in[14];
  const float* b0    = (const float*)d_in[15];
  const float* ensw  = (const float*)d_in[16];
  const float* ensb  = (const float*)d_in[17];
  const float* g2    = (const float*)d_in[18];
  const float* b2n   = (const float*)d_in[19];
  float* out = (float*)d_out;
  float* ws  = (float*)d_ws;

  hipFuncSetAttribute((const void*)kA, hipFuncAttributeMaxDynamicSharedMemorySize, LDS_DYN);
  hipFuncSetAttribute((const void*)kB, hipFuncAttributeMaxDynamicSharedMemorySize, LDS_DYN);

  k_xm<<<8192, 256, 0, stream>>>(x0, out, ws);
  k_gram<<<256, 512, 0, stream>>>(x0, out + DO_GP);
  k_prep<<<16, 256, 0, stream>>>(DA, w3, ensw, ws);
  k_att<<<384, 256, 0, stream>>>(out, w1, b1, w2, b2, w4, b4, Ag, alpha, b3, ws);
  k_gred<<<17, 256, 0, stream>>>(out);
  k_bnstat<<<12, 256, 0, stream>>>(out, Lw, g0, b0, ws);
  k_cb<<<1, 256, 0, stream>>>(ws);
  kA<<<1024, 512, LDS_DYN, stream>>>(x0, ws);
  kB<<<1024, 512, LDS_DYN, stream>>>(x0, ws, ensb, out);
  k_bn2<<<64, 256, 0, stream>>>(g2, b2n, ws);
  k_final<<<25600, 256, 0, stream>>>(x0, ws, out);
}

// Round 6
// 330.775 us; speedup vs baseline: 38.4809x; 1.2304x over previous
//
#include <hip/hip_runtime.h>
#include <cstddef>
#include <cstring>

typedef _Float16 h8 __attribute__((ext_vector_type(8)));
typedef _Float16 h4v __attribute__((ext_vector_type(4)));
typedef float f4 __attribute__((ext_vector_type(4)));
typedef unsigned int u32;
typedef unsigned short u16;

#define MTOT 409600.0f

// ---- d_out scratch offsets (floats); overwritten by k_final at the end ----
#define DO_XM  15360000            // [128][64][25] = 204,800
#define DO_GP  15564800            // [256][4096] = 1,048,576
#define DO_GR  16613376            // reduced Gram [4096] + M1 [64]

// ---- ws float offsets ----
#define WS_OB16 0               // f16 [128][64][128][25] = 13,107,200 floats
#define WS_ATT  13631488        // f16 [128][3][64][25][32]
#define WS_ATTB 23461888        // f32 [128][64][25]
#define WS_BN2P 23666688        // f32 [1024][128]
#define WS_PAR  23827456        // f32 a2[64] b2c[64] a1[192] b1c[192] = 512
#define WS_CSN  23828000        // f32 [600]

// f16-unit offsets (2x float offsets)
#define ATT_H 27262976
#define NAB_H 47595520          // f16 [3][8][32][32]
#define CB_H  47620096          // f16 [64][32]
#define WA_H  47622144          // f16 [3][64][64]
#define W3_H  47634432          // f16 [3][64][64]
#define EW_H  47646720          // f16 [64][128]

#define LDS_DYN 116736   // XsT[400][64]f16 (51200) + H[64][16][32]f16 (65536)

// ============ K1: Gram partials via MFMA (f16 in, f32 acc) ============
__global__ __launch_bounds__(512) void k_gram(const float* __restrict__ x0,
                                              float* __restrict__ gp) {
  __shared__ _Float16 Xs[64 * 128];  // 16 KB, row=256B, XOR-swizzled
  char* smb = (char*)Xs;
  int bid = blockIdx.x, tid = threadIdx.x;
  int n = bid >> 1, sh = bid & 1;
  int base = sh * 1536;
  int niter = sh ? 13 : 12;          // 1536 + 1664 = 3200
  const float* xb = x0 + (size_t)n * 204800;
  int wid = tid >> 6, lane = tid & 63, l15 = lane & 15, l4 = lane >> 4;
  int ca = (wid & 3) * 16;
  int jb0 = (wid >> 2) * 2;
  f4 acc[2] = {{0.f, 0.f, 0.f, 0.f}, {0.f, 0.f, 0.f, 0.f}};
  int sc = tid >> 3, scol = (tid & 7) * 16;
  int swz = (sc & 7) << 4;
  for (int it = 0; it < niter; ++it) {
    int s0 = base + it * 128;
    __syncthreads();
    const float* src = xb + sc * 3200 + s0 + scol;
#pragma unroll
    for (int j = 0; j < 4; ++j) {
      float4 f = *(const float4*)(src + j * 4);
      h4v hv = {(_Float16)f.x, (_Float16)f.y, (_Float16)f.z, (_Float16)f.w};
      *(h4v*)(smb + sc * 256 + (((scol + j * 4) * 2) ^ swz)) = hv;
    }
    __syncthreads();
#pragma unroll
    for (int kk = 0; kk < 4; ++kk) {
      int kb = kk * 64 + l4 * 16;
      int arow = ca + l15;
      h8 af = *(const h8*)(smb + arow * 256 + (kb ^ ((arow & 7) << 4)));
#pragma unroll
      for (int j = 0; j < 2; ++j) {
        int brow = (jb0 + j) * 16 + l15;
        h8 bf = *(const h8*)(smb + brow * 256 + (kb ^ ((brow & 7) << 4)));
        acc[j] = __builtin_amdgcn_mfma_f32_16x16x32_f16(af, bf, acc[j], 0, 0, 0);
      }
    }
  }
  float* o = gp + (size_t)bid * 4096;
#pragma unroll
  for (int j = 0; j < 2; ++j)
#pragma unroll
    for (int q = 0; q < 4; ++q)
      o[(ca + l4 * 4 + q) * 64 + (jb0 + j) * 16 + l15] = acc[j][q];
}

// ============ K1b: reduce 256 Gram partials + M1 from xm ============
__global__ __launch_bounds__(256) void k_gred(float* __restrict__ dsc) {
  int bid = blockIdx.x, tid = threadIdx.x;
  if (bid < 16) {
    int idx = bid * 256 + tid;
    const float* gp = dsc + DO_GP;
    float s0 = 0.f, s1 = 0.f, s2 = 0.f, s3 = 0.f;
    for (int b = 0; b < 256; b += 4) {
      s0 += gp[(size_t)b * 4096 + idx];
      s1 += gp[(size_t)(b + 1) * 4096 + idx];
      s2 += gp[(size_t)(b + 2) * 4096 + idx];
      s3 += gp[(size_t)(b + 3) * 4096 + idx];
    }
    dsc[DO_GR + idx] = (s0 + s1) + (s2 + s3);
  } else {
    __shared__ float red[64][5];
    int c = tid >> 2, j = tid & 3;
    float s = 0.f;
    for (int nn = j; nn < 128; nn += 4) {
      const float* xmp = dsc + DO_XM + (size_t)(nn * 64 + c) * 25;
      for (int v = 0; v < 25; ++v) s += xmp[v];
    }
    red[c][j] = s;
    __syncthreads();
    if (j == 0)
      dsc[DO_GR + 4096 + c] = 128.f * (red[c][0] + red[c][1] + red[c][2] + red[c][3]);
  }
}

// ============ K3: xm = mean over T; also zero attB ============
__global__ __launch_bounds__(256) void k_xm(const float* __restrict__ x0,
                                            float* __restrict__ dsc,
                                            float* __restrict__ ws) {
  __shared__ float red[8][32];
  int bid = blockIdx.x;
  int gid = bid * 256 + threadIdx.x;
  if (gid < 204800) ws[WS_ATTB + gid] = 0.f;
  int n = bid >> 6, c = bid & 63;
  int tid = threadIdx.x;
  int tq = tid >> 5, v = tid & 31;
  const float* xb = x0 + (size_t)(n * 64 + c) * 3200;
  float s = 0.f;
  if (v < 25) {
    for (int j = 0; j < 16; j++) s += xb[(tq + 8 * j) * 25 + v];
  }
  red[tq][v] = s;
  __syncthreads();
  if (tq == 0 && v < 25) {
    float tot = 0.f;
#pragma unroll
    for (int q = 0; q < 8; q++) tot += red[q][v];
    dsc[DO_XM + (size_t)(n * 64 + c) * 25 + v] = tot * (1.0f / 128.0f);
  }
}

// ===== K2a: parallel prep — norm_A->NAB f16 + csn; W3/EW f16 copies =====
__global__ __launch_bounds__(256) void k_prep(const float* __restrict__ DA,
                                              const float* __restrict__ w3,
                                              const float* __restrict__ ensw,
                                              float* __restrict__ wsF) {
  int bid = blockIdx.x, tid = threadIdx.x;
  _Float16* wsH = (_Float16*)wsF;
  if (bid < 3) {
    if (tid < 200) {
      int k = bid, g = tid / 25, w = tid % 25;
      const float* base = DA + (k * 8 + g) * 625 + w;
      float s = 0.f;
      for (int v = 0; v < 25; v++) s += base[v * 25];
      float inv = 1.0f / (s + 0.001f);
      wsF[WS_CSN + k * 200 + g * 25 + w] = s * inv;
      _Float16* dst = wsH + NAB_H + (size_t)((k * 8 + g) * 32 + w) * 32;
      for (int v = 0; v < 25; v++) dst[v] = (_Float16)(base[v * 25] * inv);
      for (int v = 25; v < 32; v++) dst[v] = (_Float16)0.f;
    }
  } else if (bid == 3) {
    for (int idx = tid; idx < 5376; idx += 256) {  // pad rows w=25..31
      int kg = idx / 224, r = idx % 224;
      int w = 25 + r / 32, v = r & 31;
      wsH[NAB_H + (size_t)(kg * 32 + w) * 32 + v] = (_Float16)0.f;
    }
  } else if (bid < 12) {
    int i0 = (bid - 4) * 1536;
    for (int i = tid; i < 1536; i += 256)
      wsH[W3_H + i0 + i] = (_Float16)w3[i0 + i];
  } else {
    int i0 = (bid - 12) * 2048;
    for (int i = tid; i < 2048; i += 256)
      wsH[EW_H + i0 + i] = (_Float16)ensw[i0 + i];
  }
}

// ===== K2b: BN1 stats (y^T G y per d) + folded WA rows =====
__global__ __launch_bounds__(256) void k_bnstat(const float* __restrict__ dsc,
                                                const float* __restrict__ Lw,
                                                const float* __restrict__ g0,
                                                const float* __restrict__ b0,
                                                float* __restrict__ wsF) {
  __shared__ float Gsh[64 * 66];
  __shared__ float Ly[64][17];
  __shared__ float part[16][17];
  __shared__ float a1L[16];
  int bid = blockIdx.x, tid = threadIdx.x;
  int d0 = bid * 16, dl = tid >> 4, r = tid & 15, d = d0 + dl;
  for (int idx = tid; idx < 4096; idx += 256)
    Gsh[(idx >> 6) * 66 + (idx & 63)] = dsc[DO_GR + idx];
  for (int idx = tid; idx < 1024; idx += 256)
    Ly[idx >> 4][idx & 15] = Lw[(idx >> 4) * 192 + d0 + (idx & 15)];
  __syncthreads();
  float acc = 0.f;
#pragma unroll
  for (int cc = 0; cc < 4; ++cc) {
    int c = r * 4 + cc;
    float h = 0.f;
    for (int c2 = 0; c2 < 64; ++c2) h += Gsh[c * 66 + c2] * Ly[c2][dl];
    acc += Ly[c][dl] * h;
  }
  part[dl][r] = acc;
  __syncthreads();
  if (r == 0) {
    float ex2 = 0.f;
#pragma unroll
    for (int i = 0; i < 16; ++i) ex2 += part[dl][i];
    ex2 *= (1.0f / MTOT);
    float mu = 0.f;
    for (int c = 0; c < 64; ++c) mu += dsc[DO_GR + 4096 + c] * Ly[c][dl];
    mu *= (1.0f / MTOT);
    float var = ex2 - mu * mu;
    float a1 = g0[d] * rsqrtf(var + 1e-5f);
    float b1c = b0[d] - a1 * mu;  // Linear_bias cancels in training-mode BN
    wsF[WS_PAR + 128 + d] = a1;
    wsF[WS_PAR + 320 + d] = b1c;
    a1L[dl] = a1;
  }
  __syncthreads();
  _Float16* wsH = (_Float16*)wsF;
  int k = d >> 6, cg = d & 63;
  float a1v = a1L[dl];
#pragma unroll
  for (int j = 0; j < 4; ++j) {
    int e = r * 4 + j;
    wsH[WA_H + k * 4096 + cg * 64 + e] = (_Float16)(a1v * Lw[e * 192 + d]);
  }
}

// ===== K2c: cb[c][w] from b1c and csn =====
__global__ __launch_bounds__(256) void k_cb(float* __restrict__ wsF) {
  int tid = threadIdx.x;
  _Float16* wsH = (_Float16*)wsF;
  for (int idx = tid; idx < 2048; idx += 256) {
    int c = idx >> 5, w = idx & 31;
    float s = 0.f;
    if (w < 25) {
      int g = c & 7;
      for (int k = 0; k < 3; ++k)
        s += wsF[WS_PAR + 320 + k * 64 + c] * wsF[WS_CSN + k * 200 + g * 25 + w];
    }
    wsH[CB_H + idx] = (_Float16)s;
  }
}

// ============ K4: attention -> attT f16 [n][i][c][v=w][u pad32] + attB ============
__global__ __launch_bounds__(256) void k_att(const float* __restrict__ dsc,
    const float* __restrict__ w1, const float* __restrict__ b1,
    const float* __restrict__ w2, const float* __restrict__ b2,
    const float* __restrict__ w4, const float* __restrict__ b4,
    const float* __restrict__ Ag, const float* __restrict__ alpha,
    const float* __restrict__ b3, float* __restrict__ wsF) {
  __shared__ float xms[1600];
  __shared__ float x1s[200];
  __shared__ float x2s[200];
  __shared__ float Td[5000];
  int bid = blockIdx.x, tid = threadIdx.x;
  int n = bid / 3, i = bid % 3;
  for (int idx = tid; idx < 1600; idx += 256)
    xms[idx] = dsc[DO_XM + (size_t)n * 1600 + idx];
  __syncthreads();
  for (int idx = tid; idx < 400; idx += 256) {
    int r = (idx % 200) / 25, u = idx % 25;
    const float* wv = (idx < 200 ? w1 : w2) + (i * 8 + r) * 64;
    float acc = (idx < 200 ? b1 : b2)[i * 8 + r];
    for (int c = 0; c < 64; c++) acc += xms[c * 25 + u] * wv[c];
    if (idx < 200) x1s[r * 25 + u] = acc; else x2s[r * 25 + u] = acc;
  }
  __syncthreads();
  for (int idx = tid; idx < 5000; idx += 256) {
    int r = idx / 625, u = (idx % 625) / 25, w = idx % 25;
    Td[idx] = tanhf(x1s[r * 25 + u] - x2s[r * 25 + w]);
  }
  __syncthreads();
  float al = alpha[0];
  u32* attW = (u32*)wsF;
  for (int p = tid; p < 1600; p += 256) {
    int o = p / 25, w = p % 25;
    float w4r[8];
#pragma unroll
    for (int r = 0; r < 8; r++) w4r[r] = w4[(i * 64 + o) * 8 + r];
    float b4v = b4[i * 64 + o];
    const float* AgW = Ag + i * 625 + w;
    float asum = 0.f;
    size_t rowH = (size_t)ATT_H + ((size_t)((n * 3 + i) * 64 + o) * 25 + w) * 32;
    u32* row = attW + rowH / 2;
    for (int up = 0; up < 16; ++up) {
      u32 word = 0;
#pragma unroll
      for (int h = 0; h < 2; ++h) {
        int u = up * 2 + h;
        float v = 0.f;
        if (u < 25) {
          float acc = b4v;
#pragma unroll
          for (int r = 0; r < 8; r++) acc += w4r[r] * Td[r * 625 + u * 25 + w];
          v = al * acc + AgW[u * 25];
          asum += v;
        }
        union { _Float16 hf; u16 b; } cv;
        cv.hf = (_Float16)v;
        word |= ((u32)cv.b) << (16 * h);
      }
      row[up] = word;
    }
    atomicAdd(&wsF[WS_ATTB + (size_t)n * 1600 + p], b3[i * 64 + o] * asum);
  }
}

// ---- shared device helpers for kAB ----
__device__ __forceinline__ void stageX(const float* __restrict__ xn, char* sm, int tid) {
  for (int idx = tid; idx < 25600; idx += 512) {
    int c = idx / 400, s = idx % 400;
    float f = xn[c * 3200 + s];
    *(_Float16*)(sm + s * 128 + ((c * 2) ^ ((s & 7) << 4))) = (_Float16)f;
  }
}
__device__ __forceinline__ void zeroHpads(char* sm, int tid) {
  for (int idx = tid; idx < 7168; idx += 512) {
    int c = idx / 112, r = idx % 112;
    int t = r / 7, u = 25 + r % 7;
    int hs = (((t & 3) ^ ((c >> 2) & 3)) << 4);
    *(_Float16*)(sm + 51200 + c * 1024 + t * 64 + ((u * 2) ^ hs)) = (_Float16)0.f;
  }
}
// 64-row GEMM: H[c][t][u] = sum_e A[c][e] * XsT[s][e]
__device__ __forceinline__ void gemm64(const _Float16* __restrict__ Aw, char* sm,
                                       int wid, int lane) {
  int l15 = lane & 15, l4 = lane >> 4;
  int mt = wid & 3, half = wid >> 2;
  h8 a0 = *(const h8*)(Aw + (mt * 16 + l15) * 64 + l4 * 8);
  h8 a1 = *(const h8*)(Aw + (mt * 16 + l15) * 64 + 32 + l4 * 8);
  int nt0 = half * 13, nt1 = 13 + half * 12;
  for (int nt = nt0; nt < nt1; ++nt) {
    int s = nt * 16 + l15;
    int sw = (s & 7) << 4;
    const char* rb = sm + s * 128;
    h8 b0 = *(const h8*)(rb + ((l4 * 16) ^ sw));
    h8 b1 = *(const h8*)(rb + ((64 + l4 * 16) ^ sw));
    f4 acc = {0.f, 0.f, 0.f, 0.f};
    acc = __builtin_amdgcn_mfma_f32_16x16x32_f16(a0, b0, acc, 0, 0, 0);
    acc = __builtin_amdgcn_mfma_f32_16x16x32_f16(a1, b1, acc, 0, 0, 0);
    int t = s / 25, u = s % 25;
#pragma unroll
    for (int q = 0; q < 4; ++q) {
      int c = mt * 16 + l4 * 4 + q;
      int hs = (((t & 3) ^ ((c >> 2) & 3)) << 4);
      *(_Float16*)(sm + 51200 + c * 1024 + t * 64 + ((u * 2) ^ hs)) = (_Float16)acc[q];
    }
  }
}

// ===== kAB: fused — stage x0 once; xb (WA×3 + NAB) and y (W3×3 + attT)
//       accumulated in regs; cat in LDS; ensemble GEMM; f16 out_pre + BN2 partials
__global__ __launch_bounds__(512) void kAB(const float* __restrict__ x0,
                                           float* ws,
                                           const float* __restrict__ ensb) {
  extern __shared__ char sm[];
  __shared__ float redS[128];
  __shared__ float attBs[1600];
  const _Float16* wsH = (const _Float16*)ws;
  int tid = threadIdx.x, bid = blockIdx.x;
  int lb = (bid & 7) * 128 + (bid >> 3);
  int n = lb >> 3, tile = lb & 7;
  int wid = tid >> 6, lane = tid & 63, l15 = lane & 15, l4 = lane >> 4;
  if (tid < 128) redS[tid] = 0.f;
  for (int idx = tid; idx < 1600; idx += 512)
    attBs[idx] = ws[WS_ATTB + (size_t)n * 1600 + idx];
  stageX(x0 + (size_t)n * 204800 + tile * 400, sm, tid);
  zeroHpads(sm, tid);
  __syncthreads();
  f4 accx[8][2], accy[8][2];
#pragma unroll
  for (int a = 0; a < 8; a++)
#pragma unroll
    for (int b = 0; b < 2; b++) {
      accx[a][b] = (f4){0.f, 0.f, 0.f, 0.f};
      accy[a][b] = (f4){0.f, 0.f, 0.f, 0.f};
    }
  // ---- xb branch: 3 × (Linear GEMM; contract with norm_A) ----
  for (int k = 0; k < 3; ++k) {
    gemm64(wsH + WA_H + k * 4096, sm, wid, lane);
    __syncthreads();
#pragma unroll
    for (int mt2 = 0; mt2 < 8; ++mt2) {
      int c = mt2 * 8 + wid;
      int hs = (((l15 & 3) ^ ((c >> 2) & 3)) << 4);
      h8 aH = *(const h8*)(sm + 51200 + c * 1024 + l15 * 64 + ((l4 * 16) ^ hs));
#pragma unroll
      for (int nt2 = 0; nt2 < 2; ++nt2) {
        const _Float16* nb = wsH + NAB_H +
            (size_t)((k * 8 + wid) * 32 + nt2 * 16 + l15) * 32 + l4 * 8;
        accx[mt2][nt2] = __builtin_amdgcn_mfma_f32_16x16x32_f16(
            aH, *(const h8*)nb, accx[mt2][nt2], 0, 0, 0);
      }
    }
    __syncthreads();
  }
  // ---- y branch: 3 × (x3 GEMM; contract with att) ----
  for (int i = 0; i < 3; ++i) {
    gemm64(wsH + W3_H + i * 4096, sm, wid, lane);
    __syncthreads();
#pragma unroll
    for (int mt2 = 0; mt2 < 8; ++mt2) {
      int c = mt2 * 8 + wid;
      int hs = (((l15 & 3) ^ ((c >> 2) & 3)) << 4);
      h8 aX = *(const h8*)(sm + 51200 + c * 1024 + l15 * 64 + ((l4 * 16) ^ hs));
#pragma unroll
      for (int nt2 = 0; nt2 < 2; ++nt2) {
        int v = nt2 * 16 + l15;
        int vc = v < 25 ? v : 0;
        const _Float16* ab = wsH + ATT_H +
            ((size_t)((n * 3 + i) * 64 + c) * 25 + vc) * 32 + l4 * 8;
        accy[mt2][nt2] = __builtin_amdgcn_mfma_f32_16x16x32_f16(
            aX, *(const h8*)ab, accy[mt2][nt2], 0, 0, 0);
      }
    }
    __syncthreads();
  }
  // ---- build catT[400][128] f16 (swizzled) over the XsT/H region ----
#pragma unroll
  for (int mt2 = 0; mt2 < 8; ++mt2) {
    int c = mt2 * 8 + wid;
#pragma unroll
    for (int nt2 = 0; nt2 < 2; ++nt2) {
      int w = nt2 * 16 + l15;
      if (w < 25) {
        float cbv = (float)wsH[CB_H + c * 32 + w];
        float abv = attBs[c * 25 + w];
#pragma unroll
        for (int q = 0; q < 4; ++q) {
          int t = l4 * 4 + q;
          int s = t * 25 + w;
          int sw = (s & 7) << 4;
          *(_Float16*)(sm + s * 256 + ((c * 2) ^ sw)) =
              (_Float16)(accx[mt2][nt2][q] + cbv);
          *(_Float16*)(sm + s * 256 + (((64 + c) * 2) ^ sw)) =
              (_Float16)(accy[mt2][nt2][q] + abv);
        }
      }
    }
  }
  __syncthreads();
  // ---- ensemble GEMM (K=128) -> f16 out_pre + BN2 partials ----
  int mt = wid & 3, half = wid >> 2;
  h8 ea[4];
#pragma unroll
  for (int ks = 0; ks < 4; ++ks)
    ea[ks] = *(const h8*)(wsH + EW_H + (mt * 16 + l15) * 128 + ks * 32 + l4 * 8);
  float eb[4];
#pragma unroll
  for (int q = 0; q < 4; ++q) eb[q] = ensb[mt * 16 + l4 * 4 + q];
  float lsum[4] = {0.f, 0.f, 0.f, 0.f}, lss[4] = {0.f, 0.f, 0.f, 0.f};
  u16* ob16 = (u16*)ws;
  int nt0 = half * 13, nt1 = 13 + half * 12;
  for (int nt = nt0; nt < nt1; ++nt) {
    int s = nt * 16 + l15;
    int sw = (s & 7) << 4;
    f4 acc = {0.f, 0.f, 0.f, 0.f};
#pragma unroll
    for (int ks = 0; ks < 4; ++ks) {
      h8 b = *(const h8*)(sm + s * 256 + (((ks * 32 + l4 * 8) * 2) ^ sw));
      acc = __builtin_amdgcn_mfma_f32_16x16x32_f16(ea[ks], b, acc, 0, 0, 0);
    }
    size_t ob = (size_t)n * 204800 + (size_t)tile * 400 + s;
#pragma unroll
    for (int q = 0; q < 4; ++q) {
      int o = mt * 16 + l4 * 4 + q;
      union { _Float16 hf; u16 b; } cv;
      cv.hf = (_Float16)(acc[q] + eb[q]);
      ob16[ob + (size_t)o * 3200] = cv.b;
      float val = (float)cv.hf;
      lsum[q] += val;
      lss[q] += val * val;
    }
  }
#pragma unroll
  for (int q = 0; q < 4; ++q) {
    int o = mt * 16 + l4 * 4 + q;
    atomicAdd(&redS[o], lsum[q]);
    atomicAdd(&redS[64 + o], lss[q]);
  }
  __syncthreads();
  if (tid < 64) {
    ws[WS_BN2P + (size_t)bid * 128 + tid * 2] = redS[tid];
    ws[WS_BN2P + (size_t)bid * 128 + tid * 2 + 1] = redS[64 + tid];
  }
}

// ============ K9: BN2 reduce (parallel, one block per channel) ============
__global__ __launch_bounds__(256) void k_bn2(const float* __restrict__ g2,
                                             const float* __restrict__ b2,
                                             float* __restrict__ ws) {
  __shared__ float rs[256], rss[256];
  int o = blockIdx.x, tid = threadIdx.x;
  float s = 0.f, ss = 0.f;
  for (int b = tid; b < 1024; b += 256) {
    s += ws[WS_BN2P + (size_t)b * 128 + o * 2];
    ss += ws[WS_BN2P + (size_t)b * 128 + o * 2 + 1];
  }
  rs[tid] = s; rss[tid] = ss;
  __syncthreads();
  for (int st = 128; st > 0; st >>= 1) {
    if (tid < st) { rs[tid] += rs[tid + st]; rss[tid] += rss[tid + st]; }
    __syncthreads();
  }
  if (tid == 0) {
    float mu = rs[0] / MTOT;
    float var = rss[0] / MTOT - mu * mu;
    float a2 = g2[o] * rsqrtf(var + 1e-5f);
    ws[WS_PAR + o] = a2;
    ws[WS_PAR + 64 + o] = b2[o] - a2 * mu;
  }
}

// ============ K10: BN2 apply + residual + ReLU (reads f16 out_pre) ============
__global__ __launch_bounds__(256) void k_final(const float* __restrict__ x0,
                                               const float* __restrict__ ws,
                                               float* __restrict__ dout) {
  size_t g = (size_t)blockIdx.x * 256 + threadIdx.x;
  h4v p = reinterpret_cast<const h4v*>(ws)[g];
  float4 x = reinterpret_cast<const float4*>(x0)[g];
  int o = (int)((g * 4 / 3200) & 63);
  float a2 = ws[WS_PAR + o], bc = ws[WS_PAR + 64 + o];
  float4 r;
  r.x = fmaxf(fmaf(a2, (float)p[0], bc) + x.x, 0.f);
  r.y = fmaxf(fmaf(a2, (float)p[1], bc) + x.y, 0.f);
  r.z = fmaxf(fmaf(a2, (float)p[2], bc) + x.z, 0.f);
  r.w = fmaxf(fmaf(a2, (float)p[3], bc) + x.w, 0.f);
  reinterpret_cast<float4*>(dout)[g] = r;
}

extern "C" void kernel_launch(void* const* d_in, const int* in_sizes, int n_in,
                              void* d_out, int out_size, void* d_ws, size_t ws_size,
                              hipStream_t stream) {
  const float* x0    = (const float*)d_in[0];
  const float* DA    = (const float*)d_in[1];
  const float* Ag    = (const float*)d_in[2];
  const float* alpha = (const float*)d_in[3];
  const float* w1    = (const float*)d_in[4];
  const float* b1    = (const float*)d_in[5];
  const float* w2    = (const float*)d_in[6];
  const float* b2    = (const float*)d_in[7];
  const float* w3    = (const float*)d_in[8];
  const float* b3    = (const float*)d_in[9];
  const float* w4    = (const float*)d_in[10];
  const float* b4    = (const float*)d_in[11];
  const float* Lw    = (const float*)d_in[12];
  // d_in[13] Linear_bias: cancels under training-mode BN — unused
  const float* g0    = (const float*)d_in[14];
  const float* b0    = (const float*)d_in[15];
  const float* ensw  = (const float*)d_in[16];
  const float* ensb  = (const float*)d_in[17];
  const float* g2    = (const float*)d_in[18];
  const float* b2n   = (const float*)d_in[19];
  float* out = (float*)d_out;
  float* ws  = (float*)d_ws;

  hipFuncSetAttribute((const void*)kAB, hipFuncAttributeMaxDynamicSharedMemorySize, LDS_DYN);

  k_xm<<<8192, 256, 0, stream>>>(x0, out, ws);
  k_gram<<<256, 512, 0, stream>>>(x0, out + DO_GP);
  k_prep<<<16, 256, 0, stream>>>(DA, w3, ensw, ws);
  k_att<<<384, 256, 0, stream>>>(out, w1, b1, w2, b2, w4, b4, Ag, alpha, b3, ws);
  k_gred<<<17, 256, 0, stream>>>(out);
  k_bnstat<<<12, 256, 0, stream>>>(out, Lw, g0, b0, ws);
  k_cb<<<1, 256, 0, stream>>>(ws);
  kAB<<<1024, 512, LDS_DYN, stream>>>(x0, ws, ensb);
  k_bn2<<<64, 256, 0, stream>>>(g2, b2n, ws);
  k_final<<<25600, 256, 0, stream>>>(x0, ws, out);
}

// Round 7
// 300.479 us; speedup vs baseline: 42.3607x; 1.1008x over previous
//
#include <hip/hip_runtime.h>
#include <cstddef>
#include <cstring>

typedef _Float16 h8 __attribute__((ext_vector_type(8)));
typedef _Float16 h4v __attribute__((ext_vector_type(4)));
typedef float f4 __attribute__((ext_vector_type(4)));
typedef unsigned int u32;
typedef unsigned short u16;

#define MTOT 409600.0f

// ---- d_out scratch offsets (floats); overwritten by k_final at the end ----
#define DO_XM  15360000            // [128][64][25] = 204,800
#define DO_GP  15564800            // [256][4096] = 1,048,576
#define DO_GR  16613376            // reduced Gram [4096] + M1 [64]

// ---- ws float offsets ----
#define WS_OB16 0               // f16 [128][64][128][25] = 13,107,200 floats
#define WS_ATT  13631488        // f16 [128][3][64][25][32]
#define WS_ATTB 23461888        // f32 [128][64][25]
#define WS_BN2P 23666688        // f32 [1024][128]
#define WS_PAR  23827456        // f32 a2[64] b2c[64] a1[192] b1c[192] = 512
#define WS_CSN  23828000        // f32 [600]

// f16-unit offsets (2x float offsets)
#define ATT_H 27262976
#define NAB_H 47595520          // f16 [3][8][32][32]
#define CB_H  47620096          // f16 [64][32]
#define WA_H  47622144          // f16 [3][64][64]
#define W3_H  47634432          // f16 [3][64][64]
#define EW_H  47646720          // f16 [64][128]

#define LDS_DYN 116736   // XsT[400][64]f16 (51200) + H[64][16][32]f16 (65536)

// ============ K1: Gram partials via MFMA (f16 in, f32 acc) ============
__global__ __launch_bounds__(512) void k_gram(const float* __restrict__ x0,
                                              float* __restrict__ gp) {
  __shared__ _Float16 Xs[64 * 128];  // 16 KB, row=256B, XOR-swizzled
  char* smb = (char*)Xs;
  int bid = blockIdx.x, tid = threadIdx.x;
  int n = bid >> 1, sh = bid & 1;
  int base = sh * 1536;
  int niter = sh ? 13 : 12;          // 1536 + 1664 = 3200
  const float* xb = x0 + (size_t)n * 204800;
  int wid = tid >> 6, lane = tid & 63, l15 = lane & 15, l4 = lane >> 4;
  int ca = (wid & 3) * 16;
  int jb0 = (wid >> 2) * 2;
  f4 acc[2] = {{0.f, 0.f, 0.f, 0.f}, {0.f, 0.f, 0.f, 0.f}};
  int sc = tid >> 3, scol = (tid & 7) * 16;
  int swz = (sc & 7) << 4;
  for (int it = 0; it < niter; ++it) {
    int s0 = base + it * 128;
    __syncthreads();
    const float* src = xb + sc * 3200 + s0 + scol;
#pragma unroll
    for (int j = 0; j < 4; ++j) {
      float4 f = *(const float4*)(src + j * 4);
      h4v hv = {(_Float16)f.x, (_Float16)f.y, (_Float16)f.z, (_Float16)f.w};
      *(h4v*)(smb + sc * 256 + (((scol + j * 4) * 2) ^ swz)) = hv;
    }
    __syncthreads();
#pragma unroll
    for (int kk = 0; kk < 4; ++kk) {
      int kb = kk * 64 + l4 * 16;
      int arow = ca + l15;
      h8 af = *(const h8*)(smb + arow * 256 + (kb ^ ((arow & 7) << 4)));
#pragma unroll
      for (int j = 0; j < 2; ++j) {
        int brow = (jb0 + j) * 16 + l15;
        h8 bf = *(const h8*)(smb + brow * 256 + (kb ^ ((brow & 7) << 4)));
        acc[j] = __builtin_amdgcn_mfma_f32_16x16x32_f16(af, bf, acc[j], 0, 0, 0);
      }
    }
  }
  float* o = gp + (size_t)bid * 4096;
#pragma unroll
  for (int j = 0; j < 2; ++j)
#pragma unroll
    for (int q = 0; q < 4; ++q)
      o[(ca + l4 * 4 + q) * 64 + (jb0 + j) * 16 + l15] = acc[j][q];
}

// ============ K1b: reduce 256 Gram partials + M1 from xm ============
__global__ __launch_bounds__(256) void k_gred(float* __restrict__ dsc) {
  int bid = blockIdx.x, tid = threadIdx.x;
  if (bid < 16) {
    int idx = bid * 256 + tid;
    const float* gp = dsc + DO_GP;
    float s0 = 0.f, s1 = 0.f, s2 = 0.f, s3 = 0.f;
    for (int b = 0; b < 256; b += 4) {
      s0 += gp[(size_t)b * 4096 + idx];
      s1 += gp[(size_t)(b + 1) * 4096 + idx];
      s2 += gp[(size_t)(b + 2) * 4096 + idx];
      s3 += gp[(size_t)(b + 3) * 4096 + idx];
    }
    dsc[DO_GR + idx] = (s0 + s1) + (s2 + s3);
  } else {
    __shared__ float red[64][5];
    int c = tid >> 2, j = tid & 3;
    float s = 0.f;
    for (int nn = j; nn < 128; nn += 4) {
      const float* xmp = dsc + DO_XM + (size_t)(nn * 64 + c) * 25;
      for (int v = 0; v < 25; ++v) s += xmp[v];
    }
    red[c][j] = s;
    __syncthreads();
    if (j == 0)
      dsc[DO_GR + 4096 + c] = 128.f * (red[c][0] + red[c][1] + red[c][2] + red[c][3]);
  }
}

// ============ K3: xm = mean over T; also zero attB ============
__global__ __launch_bounds__(256) void k_xm(const float* __restrict__ x0,
                                            float* __restrict__ dsc,
                                            float* __restrict__ ws) {
  __shared__ float red[8][32];
  int bid = blockIdx.x;
  int gid = bid * 256 + threadIdx.x;
  if (gid < 204800) ws[WS_ATTB + gid] = 0.f;
  int n = bid >> 6, c = bid & 63;
  int tid = threadIdx.x;
  int tq = tid >> 5, v = tid & 31;
  const float* xb = x0 + (size_t)(n * 64 + c) * 3200;
  float s = 0.f;
  if (v < 25) {
    for (int j = 0; j < 16; j++) s += xb[(tq + 8 * j) * 25 + v];
  }
  red[tq][v] = s;
  __syncthreads();
  if (tq == 0 && v < 25) {
    float tot = 0.f;
#pragma unroll
    for (int q = 0; q < 8; q++) tot += red[q][v];
    dsc[DO_XM + (size_t)(n * 64 + c) * 25 + v] = tot * (1.0f / 128.0f);
  }
}

// ===== K2a: parallel prep — norm_A->NAB f16 + csn; W3/EW f16 copies =====
__global__ __launch_bounds__(256) void k_prep(const float* __restrict__ DA,
                                              const float* __restrict__ w3,
                                              const float* __restrict__ ensw,
                                              float* __restrict__ wsF) {
  int bid = blockIdx.x, tid = threadIdx.x;
  _Float16* wsH = (_Float16*)wsF;
  if (bid < 3) {
    if (tid < 200) {
      int k = bid, g = tid / 25, w = tid % 25;
      const float* base = DA + (k * 8 + g) * 625 + w;
      float s = 0.f;
      for (int v = 0; v < 25; v++) s += base[v * 25];
      float inv = 1.0f / (s + 0.001f);
      wsF[WS_CSN + k * 200 + g * 25 + w] = s * inv;
      _Float16* dst = wsH + NAB_H + (size_t)((k * 8 + g) * 32 + w) * 32;
      for (int v = 0; v < 25; v++) dst[v] = (_Float16)(base[v * 25] * inv);
      for (int v = 25; v < 32; v++) dst[v] = (_Float16)0.f;
    }
  } else if (bid == 3) {
    for (int idx = tid; idx < 5376; idx += 256) {  // pad rows w=25..31
      int kg = idx / 224, r = idx % 224;
      int w = 25 + r / 32, v = r & 31;
      wsH[NAB_H + (size_t)(kg * 32 + w) * 32 + v] = (_Float16)0.f;
    }
  } else if (bid < 12) {
    int i0 = (bid - 4) * 1536;
    for (int i = tid; i < 1536; i += 256)
      wsH[W3_H + i0 + i] = (_Float16)w3[i0 + i];
  } else {
    int i0 = (bid - 12) * 2048;
    for (int i = tid; i < 2048; i += 256)
      wsH[EW_H + i0 + i] = (_Float16)ensw[i0 + i];
  }
}

// ===== K2b: BN1 stats (y^T G y per d) + folded WA rows =====
__global__ __launch_bounds__(256) void k_bnstat(const float* __restrict__ dsc,
                                                const float* __restrict__ Lw,
                                                const float* __restrict__ g0,
                                                const float* __restrict__ b0,
                                                float* __restrict__ wsF) {
  __shared__ float Gsh[64 * 66];
  __shared__ float Ly[64][17];
  __shared__ float part[16][17];
  __shared__ float a1L[16];
  int bid = blockIdx.x, tid = threadIdx.x;
  int d0 = bid * 16, dl = tid >> 4, r = tid & 15, d = d0 + dl;
  for (int idx = tid; idx < 4096; idx += 256)
    Gsh[(idx >> 6) * 66 + (idx & 63)] = dsc[DO_GR + idx];
  for (int idx = tid; idx < 1024; idx += 256)
    Ly[idx >> 4][idx & 15] = Lw[(idx >> 4) * 192 + d0 + (idx & 15)];
  __syncthreads();
  float acc = 0.f;
#pragma unroll
  for (int cc = 0; cc < 4; ++cc) {
    int c = r * 4 + cc;
    float h = 0.f;
    for (int c2 = 0; c2 < 64; ++c2) h += Gsh[c * 66 + c2] * Ly[c2][dl];
    acc += Ly[c][dl] * h;
  }
  part[dl][r] = acc;
  __syncthreads();
  if (r == 0) {
    float ex2 = 0.f;
#pragma unroll
    for (int i = 0; i < 16; ++i) ex2 += part[dl][i];
    ex2 *= (1.0f / MTOT);
    float mu = 0.f;
    for (int c = 0; c < 64; ++c) mu += dsc[DO_GR + 4096 + c] * Ly[c][dl];
    mu *= (1.0f / MTOT);
    float var = ex2 - mu * mu;
    float a1 = g0[d] * rsqrtf(var + 1e-5f);
    float b1c = b0[d] - a1 * mu;  // Linear_bias cancels in training-mode BN
    wsF[WS_PAR + 128 + d] = a1;
    wsF[WS_PAR + 320 + d] = b1c;
    a1L[dl] = a1;
  }
  __syncthreads();
  _Float16* wsH = (_Float16*)wsF;
  int k = d >> 6, cg = d & 63;
  float a1v = a1L[dl];
#pragma unroll
  for (int j = 0; j < 4; ++j) {
    int e = r * 4 + j;
    wsH[WA_H + k * 4096 + cg * 64 + e] = (_Float16)(a1v * Lw[e * 192 + d]);
  }
}

// ===== K2c: cb[c][w] from b1c and csn =====
__global__ __launch_bounds__(256) void k_cb(float* __restrict__ wsF) {
  int tid = threadIdx.x;
  _Float16* wsH = (_Float16*)wsF;
  for (int idx = tid; idx < 2048; idx += 256) {
    int c = idx >> 5, w = idx & 31;
    float s = 0.f;
    if (w < 25) {
      int g = c & 7;
      for (int k = 0; k < 3; ++k)
        s += wsF[WS_PAR + 320 + k * 64 + c] * wsF[WS_CSN + k * 200 + g * 25 + w];
    }
    wsH[CB_H + idx] = (_Float16)s;
  }
}

// ============ K4: attention -> attT f16 [n][i][c][v=w][u pad32] + attB ============
__global__ __launch_bounds__(256) void k_att(const float* __restrict__ dsc,
    const float* __restrict__ w1, const float* __restrict__ b1,
    const float* __restrict__ w2, const float* __restrict__ b2,
    const float* __restrict__ w4, const float* __restrict__ b4,
    const float* __restrict__ Ag, const float* __restrict__ alpha,
    const float* __restrict__ b3, float* __restrict__ wsF) {
  __shared__ float xms[1600];
  __shared__ float x1s[200];
  __shared__ float x2s[200];
  __shared__ float Td[5000];
  int bid = blockIdx.x, tid = threadIdx.x;
  int n = bid / 3, i = bid % 3;
  for (int idx = tid; idx < 1600; idx += 256)
    xms[idx] = dsc[DO_XM + (size_t)n * 1600 + idx];
  __syncthreads();
  for (int idx = tid; idx < 400; idx += 256) {
    int r = (idx % 200) / 25, u = idx % 25;
    const float* wv = (idx < 200 ? w1 : w2) + (i * 8 + r) * 64;
    float acc = (idx < 200 ? b1 : b2)[i * 8 + r];
    for (int c = 0; c < 64; c++) acc += xms[c * 25 + u] * wv[c];
    if (idx < 200) x1s[r * 25 + u] = acc; else x2s[r * 25 + u] = acc;
  }
  __syncthreads();
  for (int idx = tid; idx < 5000; idx += 256) {
    int r = idx / 625, u = (idx % 625) / 25, w = idx % 25;
    Td[idx] = tanhf(x1s[r * 25 + u] - x2s[r * 25 + w]);
  }
  __syncthreads();
  float al = alpha[0];
  u32* attW = (u32*)wsF;
  for (int p = tid; p < 1600; p += 256) {
    int o = p / 25, w = p % 25;
    float w4r[8];
#pragma unroll
    for (int r = 0; r < 8; r++) w4r[r] = w4[(i * 64 + o) * 8 + r];
    float b4v = b4[i * 64 + o];
    const float* AgW = Ag + i * 625 + w;
    float asum = 0.f;
    size_t rowH = (size_t)ATT_H + ((size_t)((n * 3 + i) * 64 + o) * 25 + w) * 32;
    u32* row = attW + rowH / 2;
    for (int up = 0; up < 16; ++up) {
      u32 word = 0;
#pragma unroll
      for (int h = 0; h < 2; ++h) {
        int u = up * 2 + h;
        float v = 0.f;
        if (u < 25) {
          float acc = b4v;
#pragma unroll
          for (int r = 0; r < 8; r++) acc += w4r[r] * Td[r * 625 + u * 25 + w];
          v = al * acc + AgW[u * 25];
          asum += v;
        }
        union { _Float16 hf; u16 b; } cv;
        cv.hf = (_Float16)v;
        word |= ((u32)cv.b) << (16 * h);
      }
      row[up] = word;
    }
    atomicAdd(&wsF[WS_ATTB + (size_t)n * 1600 + p], b3[i * 64 + o] * asum);
  }
}

// ---- shared device helpers for kAB (1024-thread version) ----
__device__ __forceinline__ void stageX(const float* __restrict__ xn, char* sm, int tid) {
  // unit = (c-group of 4, s); one swizzled b64 LDS store per unit
  for (int u = tid; u < 6400; u += 1024) {
    int cg = u / 400, s = u - cg * 400;
    int c0 = cg * 4;
    const float* p = xn + c0 * 3200 + s;
    float a = p[0], b = p[3200], c = p[6400], d = p[9600];
    h4v hv = {(_Float16)a, (_Float16)b, (_Float16)c, (_Float16)d};
    *(h4v*)(sm + s * 128 + ((c0 * 2) ^ ((s & 7) << 4))) = hv;
  }
}
__device__ __forceinline__ void zeroHpads(char* sm, int tid) {
  for (int idx = tid; idx < 7168; idx += 1024) {
    int c = idx / 112, r = idx % 112;
    int t = r / 7, u = 25 + r % 7;
    int hs = (((t & 3) ^ ((c >> 2) & 3)) << 4);
    *(_Float16*)(sm + 51200 + c * 1024 + t * 64 + ((u * 2) ^ hs)) = (_Float16)0.f;
  }
}
// 64-row GEMM: H[c][t][u] = sum_e A[c][e] * XsT[s][e]; wave handles (mt, nt0..nt1)
__device__ __forceinline__ void gemm64(const _Float16* __restrict__ Aw, char* sm,
                                       int mt, int nt0, int nt1, int lane) {
  int l15 = lane & 15, l4 = lane >> 4;
  h8 a0 = *(const h8*)(Aw + (mt * 16 + l15) * 64 + l4 * 8);
  h8 a1 = *(const h8*)(Aw + (mt * 16 + l15) * 64 + 32 + l4 * 8);
  for (int nt = nt0; nt < nt1; ++nt) {
    int s = nt * 16 + l15;
    int sw = (s & 7) << 4;
    const char* rb = sm + s * 128;
    h8 b0 = *(const h8*)(rb + ((l4 * 16) ^ sw));
    h8 b1 = *(const h8*)(rb + ((64 + l4 * 16) ^ sw));
    f4 acc = {0.f, 0.f, 0.f, 0.f};
    acc = __builtin_amdgcn_mfma_f32_16x16x32_f16(a0, b0, acc, 0, 0, 0);
    acc = __builtin_amdgcn_mfma_f32_16x16x32_f16(a1, b1, acc, 0, 0, 0);
    int t = s / 25, u = s % 25;
#pragma unroll
    for (int q = 0; q < 4; ++q) {
      int c = mt * 16 + l4 * 4 + q;
      int hs = (((t & 3) ^ ((c >> 2) & 3)) << 4);
      *(_Float16*)(sm + 51200 + c * 1024 + t * 64 + ((u * 2) ^ hs)) = (_Float16)acc[q];
    }
  }
}

// ===== kAB: fused — 16 waves: stage x0 once; xb (WA×3 + NAB) and y (W3×3 + attT)
//       in regs; cat in LDS; ensemble GEMM; f16 out_pre + BN2 partials
__global__ __launch_bounds__(1024, 4) void kAB(const float* __restrict__ x0,
                                               float* ws,
                                               const float* __restrict__ ensb) {
  extern __shared__ char sm[];
  __shared__ float redS[128];
  __shared__ float attBs[1600];
  const _Float16* wsH = (const _Float16*)ws;
  int tid = threadIdx.x, bid = blockIdx.x;
  int lb = (bid & 7) * 128 + (bid >> 3);
  int n = lb >> 3, tile = lb & 7;
  int wid = tid >> 6, lane = tid & 63, l15 = lane & 15, l4 = lane >> 4;
  int mt = wid & 3, q4 = wid >> 2, g = wid & 7;
  int nt0 = q4 ? 1 + 6 * q4 : 0;
  int nt1 = q4 ? nt0 + 6 : 7;
  if (tid < 128) redS[tid] = 0.f;
  for (int idx = tid; idx < 1600; idx += 1024)
    attBs[idx] = ws[WS_ATTB + (size_t)n * 1600 + idx];
  stageX(x0 + (size_t)n * 204800 + tile * 400, sm, tid);
  zeroHpads(sm, tid);
  __syncthreads();
  f4 accx[4][2], accy[4][2];
#pragma unroll
  for (int a = 0; a < 4; a++)
#pragma unroll
    for (int b = 0; b < 2; b++) {
      accx[a][b] = (f4){0.f, 0.f, 0.f, 0.f};
      accy[a][b] = (f4){0.f, 0.f, 0.f, 0.f};
    }
  // ---- xb branch: 3 × (Linear GEMM; contract with norm_A) ----
  for (int k = 0; k < 3; ++k) {
    gemm64(wsH + WA_H + k * 4096, sm, mt, nt0, nt1, lane);
    __syncthreads();
#pragma unroll
    for (int mt2 = 0; mt2 < 4; ++mt2) {
      int c = mt2 * 16 + wid;
      int hs = (((l15 & 3) ^ ((c >> 2) & 3)) << 4);
      h8 aH = *(const h8*)(sm + 51200 + c * 1024 + l15 * 64 + ((l4 * 16) ^ hs));
#pragma unroll
      for (int nt2 = 0; nt2 < 2; ++nt2) {
        const _Float16* nb = wsH + NAB_H +
            (size_t)((k * 8 + g) * 32 + nt2 * 16 + l15) * 32 + l4 * 8;
        accx[mt2][nt2] = __builtin_amdgcn_mfma_f32_16x16x32_f16(
            aH, *(const h8*)nb, accx[mt2][nt2], 0, 0, 0);
      }
    }
    __syncthreads();
  }
  // ---- y branch: 3 × (x3 GEMM; contract with att) ----
  for (int i = 0; i < 3; ++i) {
    gemm64(wsH + W3_H + i * 4096, sm, mt, nt0, nt1, lane);
    __syncthreads();
#pragma unroll
    for (int mt2 = 0; mt2 < 4; ++mt2) {
      int c = mt2 * 16 + wid;
      int hs = (((l15 & 3) ^ ((c >> 2) & 3)) << 4);
      h8 aX = *(const h8*)(sm + 51200 + c * 1024 + l15 * 64 + ((l4 * 16) ^ hs));
#pragma unroll
      for (int nt2 = 0; nt2 < 2; ++nt2) {
        int v = nt2 * 16 + l15;
        int vc = v < 25 ? v : 0;
        const _Float16* ab = wsH + ATT_H +
            ((size_t)((n * 3 + i) * 64 + c) * 25 + vc) * 32 + l4 * 8;
        accy[mt2][nt2] = __builtin_amdgcn_mfma_f32_16x16x32_f16(
            aX, *(const h8*)ab, accy[mt2][nt2], 0, 0, 0);
      }
    }
    __syncthreads();
  }
  // ---- build catT[400][128] f16 (swizzled) over the XsT/H region ----
#pragma unroll
  for (int mt2 = 0; mt2 < 4; ++mt2) {
    int c = mt2 * 16 + wid;
#pragma unroll
    for (int nt2 = 0; nt2 < 2; ++nt2) {
      int w = nt2 * 16 + l15;
      if (w < 25) {
        float cbv = (float)wsH[CB_H + c * 32 + w];
        float abv = attBs[c * 25 + w];
#pragma unroll
        for (int q = 0; q < 4; ++q) {
          int t = l4 * 4 + q;
          int s = t * 25 + w;
          int sw = (s & 7) << 4;
          *(_Float16*)(sm + s * 256 + ((c * 2) ^ sw)) =
              (_Float16)(accx[mt2][nt2][q] + cbv);
          *(_Float16*)(sm + s * 256 + (((64 + c) * 2) ^ sw)) =
              (_Float16)(accy[mt2][nt2][q] + abv);
        }
      }
    }
  }
  __syncthreads();
  // ---- ensemble GEMM (K=128) -> f16 out_pre + BN2 partials ----
  h8 ea[4];
#pragma unroll
  for (int ks = 0; ks < 4; ++ks)
    ea[ks] = *(const h8*)(wsH + EW_H + (mt * 16 + l15) * 128 + ks * 32 + l4 * 8);
  float eb[4];
#pragma unroll
  for (int q = 0; q < 4; ++q) eb[q] = ensb[mt * 16 + l4 * 4 + q];
  float lsum[4] = {0.f, 0.f, 0.f, 0.f}, lss[4] = {0.f, 0.f, 0.f, 0.f};
  u16* ob16 = (u16*)ws;
  for (int nt = nt0; nt < nt1; ++nt) {
    int s = nt * 16 + l15;
    int sw = (s & 7) << 4;
    f4 acc = {0.f, 0.f, 0.f, 0.f};
#pragma unroll
    for (int ks = 0; ks < 4; ++ks) {
      h8 b = *(const h8*)(sm + s * 256 + (((ks * 32 + l4 * 8) * 2) ^ sw));
      acc = __builtin_amdgcn_mfma_f32_16x16x32_f16(ea[ks], b, acc, 0, 0, 0);
    }
    size_t ob = (size_t)n * 204800 + (size_t)tile * 400 + s;
#pragma unroll
    for (int q = 0; q < 4; ++q) {
      int o = mt * 16 + l4 * 4 + q;
      union { _Float16 hf; u16 b; } cv;
      cv.hf = (_Float16)(acc[q] + eb[q]);
      ob16[ob + (size_t)o * 3200] = cv.b;
      float val = (float)cv.hf;
      lsum[q] += val;
      lss[q] += val * val;
    }
  }
  // wave-level reduce over the 16 l15 lanes, then one atomic per (l4,q)
#pragma unroll
  for (int q = 0; q < 4; ++q) {
#pragma unroll
    for (int d = 1; d < 16; d <<= 1) {
      lsum[q] += __shfl_xor(lsum[q], d);
      lss[q] += __shfl_xor(lss[q], d);
    }
  }
  if (l15 == 0) {
#pragma unroll
    for (int q = 0; q < 4; ++q) {
      int o = mt * 16 + l4 * 4 + q;
      atomicAdd(&redS[o], lsum[q]);
      atomicAdd(&redS[64 + o], lss[q]);
    }
  }
  __syncthreads();
  if (tid < 64) {
    ws[WS_BN2P + (size_t)bid * 128 + tid * 2] = redS[tid];
    ws[WS_BN2P + (size_t)bid * 128 + tid * 2 + 1] = redS[64 + tid];
  }
}

// ============ K9: BN2 reduce (parallel, one block per channel) ============
__global__ __launch_bounds__(256) void k_bn2(const float* __restrict__ g2,
                                             const float* __restrict__ b2,
                                             float* __restrict__ ws) {
  __shared__ float rs[256], rss[256];
  int o = blockIdx.x, tid = threadIdx.x;
  float s = 0.f, ss = 0.f;
  for (int b = tid; b < 1024; b += 256) {
    s += ws[WS_BN2P + (size_t)b * 128 + o * 2];
    ss += ws[WS_BN2P + (size_t)b * 128 + o * 2 + 1];
  }
  rs[tid] = s; rss[tid] = ss;
  __syncthreads();
  for (int st = 128; st > 0; st >>= 1) {
    if (tid < st) { rs[tid] += rs[tid + st]; rss[tid] += rss[tid + st]; }
    __syncthreads();
  }
  if (tid == 0) {
    float mu = rs[0] / MTOT;
    float var = rss[0] / MTOT - mu * mu;
    float a2 = g2[o] * rsqrtf(var + 1e-5f);
    ws[WS_PAR + o] = a2;
    ws[WS_PAR + 64 + o] = b2[o] - a2 * mu;
  }
}

// ============ K10: BN2 apply + residual + ReLU (reads f16 out_pre) ============
__global__ __launch_bounds__(256) void k_final(const float* __restrict__ x0,
                                               const float* __restrict__ ws,
                                               float* __restrict__ dout) {
  size_t g = (size_t)blockIdx.x * 256 + threadIdx.x;
  h4v p = reinterpret_cast<const h4v*>(ws)[g];
  float4 x = reinterpret_cast<const float4*>(x0)[g];
  int o = (int)((g * 4 / 3200) & 63);
  float a2 = ws[WS_PAR + o], bc = ws[WS_PAR + 64 + o];
  float4 r;
  r.x = fmaxf(fmaf(a2, (float)p[0], bc) + x.x, 0.f);
  r.y = fmaxf(fmaf(a2, (float)p[1], bc) + x.y, 0.f);
  r.z = fmaxf(fmaf(a2, (float)p[2], bc) + x.z, 0.f);
  r.w = fmaxf(fmaf(a2, (float)p[3], bc) + x.w, 0.f);
  reinterpret_cast<float4*>(dout)[g] = r;
}

extern "C" void kernel_launch(void* const* d_in, const int* in_sizes, int n_in,
                              void* d_out, int out_size, void* d_ws, size_t ws_size,
                              hipStream_t stream) {
  const float* x0    = (const float*)d_in[0];
  const float* DA    = (const float*)d_in[1];
  const float* Ag    = (const float*)d_in[2];
  const float* alpha = (const float*)d_in[3];
  const float* w1    = (const float*)d_in[4];
  const float* b1    = (const float*)d_in[5];
  const float* w2    = (const float*)d_in[6];
  const float* b2    = (const float*)d_in[7];
  const float* w3    = (const float*)d_in[8];
  const float* b3    = (const float*)d_in[9];
  const float* w4    = (const float*)d_in[10];
  const float* b4    = (const float*)d_in[11];
  const float* Lw    = (const float*)d_in[12];
  // d_in[13] Linear_bias: cancels under training-mode BN — unused
  const float* g0    = (const float*)d_in[14];
  const float* b0    = (const float*)d_in[15];
  const float* ensw  = (const float*)d_in[16];
  const float* ensb  = (const float*)d_in[17];
  const float* g2    = (const float*)d_in[18];
  const float* b2n   = (const float*)d_in[19];
  float* out = (float*)d_out;
  float* ws  = (float*)d_ws;

  hipFuncSetAttribute((const void*)kAB, hipFuncAttributeMaxDynamicSharedMemorySize, LDS_DYN);

  k_xm<<<8192, 256, 0, stream>>>(x0, out, ws);
  k_gram<<<256, 512, 0, stream>>>(x0, out + DO_GP);
  k_prep<<<16, 256, 0, stream>>>(DA, w3, ensw, ws);
  k_att<<<384, 256, 0, stream>>>(out, w1, b1, w2, b2, w4, b4, Ag, alpha, b3, ws);
  k_gred<<<17, 256, 0, stream>>>(out);
  k_bnstat<<<12, 256, 0, stream>>>(out, Lw, g0, b0, ws);
  k_cb<<<1, 256, 0, stream>>>(ws);
  kAB<<<1024, 1024, LDS_DYN, stream>>>(x0, ws, ensb);
  k_bn2<<<64, 256, 0, stream>>>(g2, b2n, ws);
  k_final<<<25600, 256, 0, stream>>>(x0, ws, out);
}